// Round 1
// 1144.069 us; speedup vs baseline: 1.0652x; 1.0652x over previous
//
#include <hip/hip_runtime.h>
#include <cstdint>
#include <cstddef>

// ---------------------------------------------------------------------------
// AutoformerEncodeBlock R6:
//  - corr_fft rewritten as register radix-8 FFT: 3 radix-2 stages per LDS
//    exchange (11 LDS round-trips -> 3.5, 12 barriers -> 5), 2 ch/block,
//    LDS 78KB -> 42KB (3 blocks/CU), pad-32 conflict-free exchanges,
//    atomics replaced by partial-spectrum rows in dead vh region + reduce.
//  - v-GEMM eliminated: agg commutes with channel mixing -> Wvo = Wo*Wv fold
//  - q,k fused into one N=2048 GEMM (transposed [B,2C,L] epilogue)
//  - FFN re-sliced: FFN1 over N, FFN2 K-partials with RMW epilogue
// ---------------------------------------------------------------------------

typedef _Float16 half8 __attribute__((ext_vector_type(8)));
typedef _Float16 half4 __attribute__((ext_vector_type(4)));
typedef float floatx4 __attribute__((ext_vector_type(4)));

#define PI_F 3.14159265358979323846f
#define ZP32(i) ((i) + ((i) >> 5))  // pad every 32 float2 elements

__device__ __forceinline__ void load_lds16(const void* g, void* l) {
  __builtin_amdgcn_global_load_lds((__attribute__((address_space(1))) void*)g,
                                   (__attribute__((address_space(3))) void*)l,
                                   16, 0, 0);
}

// ---------------------------- small utility kernels ------------------------

__global__ __launch_bounds__(256) void cvt_f16_kernel(const float* __restrict__ src,
                                                      _Float16* __restrict__ dst, int n4) {
  int i = blockIdx.x * 256 + threadIdx.x;
  if (i >= n4) return;
  float4 v = ((const float4*)src)[i];
  half4 h = {(_Float16)v.x, (_Float16)v.y, (_Float16)v.z, (_Float16)v.w};
  ((half4*)dst)[i] = h;
}

// dst[c, j] = src[j, c]  (n x n, fp32 -> fp16), 64x64 LDS tiles
__global__ __launch_bounds__(256) void transpose_f16_kernel(const float* __restrict__ src,
                                                            _Float16* __restrict__ dst, int n) {
  __shared__ float tile[64][65];
  int j0 = blockIdx.y * 64, c0 = blockIdx.x * 64;
  int tr = threadIdx.x >> 4;
  int tc = threadIdx.x & 15;
#pragma unroll
  for (int rr = 0; rr < 64; rr += 16) {
    float4 v = *(const float4*)(src + (size_t)(j0 + tr + rr) * n + c0 + tc * 4);
    tile[tr + rr][tc * 4 + 0] = v.x;
    tile[tr + rr][tc * 4 + 1] = v.y;
    tile[tr + rr][tc * 4 + 2] = v.z;
    tile[tr + rr][tc * 4 + 3] = v.w;
  }
  __syncthreads();
#pragma unroll
  for (int rr = 0; rr < 64; rr += 16) {
    int c = tr + rr;
    half4 h = {(_Float16)tile[tc * 4 + 0][c], (_Float16)tile[tc * 4 + 1][c],
               (_Float16)tile[tc * 4 + 2][c], (_Float16)tile[tc * 4 + 3][c]};
    *(half4*)(dst + (size_t)(c0 + c) * n + j0 + tc * 4) = h;
  }
}

// --------------------------------- LayerNorm -------------------------------
__global__ __launch_bounds__(256) void ln_kernel(const float* __restrict__ x,
                                                 const float* __restrict__ g,
                                                 const float* __restrict__ b,
                                                 _Float16* __restrict__ xn, int C) {
  int row = blockIdx.x;
  int t = threadIdx.x;
  const float4* xr = (const float4*)(x + (size_t)row * C);
  float4 v = xr[t];
  float s = v.x + v.y + v.z + v.w;
  float s2 = v.x * v.x + v.y * v.y + v.z * v.z + v.w * v.w;
  for (int o = 32; o > 0; o >>= 1) {
    s += __shfl_down(s, o, 64);
    s2 += __shfl_down(s2, o, 64);
  }
  __shared__ float red[8];
  int wave = t >> 6, lane = t & 63;
  if (lane == 0) { red[wave] = s; red[4 + wave] = s2; }
  __syncthreads();
  __shared__ float stats[2];
  if (t == 0) {
    float ts = red[0] + red[1] + red[2] + red[3];
    float ts2 = red[4] + red[5] + red[6] + red[7];
    float mu = ts / (float)C;
    float var = ts2 / (float)C - mu * mu;
    stats[0] = mu;
    stats[1] = 1.0f / sqrtf(var + 1e-5f);
  }
  __syncthreads();
  float mu = stats[0], rs = stats[1];
  float4 gv = ((const float4*)g)[t];
  float4 bv = ((const float4*)b)[t];
  half4 h = {(_Float16)((v.x - mu) * rs * gv.x + bv.x),
             (_Float16)((v.y - mu) * rs * gv.y + bv.y),
             (_Float16)((v.z - mu) * rs * gv.z + bv.z),
             (_Float16)((v.w - mu) * rs * gv.w + bv.w)};
  ((half4*)(xn + (size_t)row * C))[t] = h;
}

// ----------------------------------- GEMM ----------------------------------
// C[M,N] = A[M,K] * Bw[N,K]^T  (fp16). lda/ldb = row strides (K-dim).
// 128x128 tile, BK=64, 4 waves 2x2, 4x4 of 16x16x32 MFMA, global_load_lds.
// EPI: 1 = +bias[col]+res fp32, 2 = GELU -> fp16, 3 = +res fp32 (RMW ok),
//      4 = plain fp16, 5 = fp16 transposed [B, N, L] (L=2048)
template <int EPI>
__global__ __launch_bounds__(256) void gemm_kernel(
    const _Float16* __restrict__ A, const _Float16* __restrict__ Bw,
    int M, int N, int K, int lda, int ldb,
    float* __restrict__ outf, _Float16* __restrict__ outh,
    const float* __restrict__ bias, const float* __restrict__ res) {
  __shared__ _Float16 sA[128 * 64];
  __shared__ _Float16 sB[128 * 64];

  int tid = threadIdx.x;
  int lane = tid & 63;
  int wave = tid >> 6;
  int wm = wave >> 1, wn = wave & 1;
  int ln15 = lane & 15, q4 = lane >> 4;

  size_t m0 = (size_t)blockIdx.x * 128;  // x = M for XCD-local A reuse
  size_t n0 = (size_t)blockIdx.y * 128;

  floatx4 acc[4][4] = {};

  int row0 = tid >> 3;
  int col16 = tid & 7;
  const _Float16* Ab = A + (m0 + row0) * (size_t)lda + col16 * 8;
  const _Float16* Bb = Bw + (n0 + row0) * (size_t)ldb + col16 * 8;
  char* ldsA = (char*)sA + wave * 1024;  // wave-uniform; HW adds lane*16
  char* ldsB = (char*)sB + wave * 1024;

  int nk = K >> 6;
  for (int ks = 0; ks < nk; ++ks) {
    __syncthreads();
    size_t k0 = (size_t)ks << 6;
#pragma unroll
    for (int j = 0; j < 4; ++j) {
      load_lds16(Ab + k0 + (size_t)(32 * j) * lda, ldsA + j * 4096);
      load_lds16(Bb + k0 + (size_t)(32 * j) * ldb, ldsB + j * 4096);
    }
    __syncthreads();
#pragma unroll
    for (int kk = 0; kk < 64; kk += 32) {
      half8 af[4], bf[4];
#pragma unroll
      for (int mi = 0; mi < 4; ++mi)
        af[mi] = *(const half8*)(sA + (wm * 64 + mi * 16 + ln15) * 64 + kk + q4 * 8);
#pragma unroll
      for (int ni = 0; ni < 4; ++ni)
        bf[ni] = *(const half8*)(sB + (wn * 64 + ni * 16 + ln15) * 64 + kk + q4 * 8);
#pragma unroll
      for (int mi = 0; mi < 4; ++mi)
#pragma unroll
        for (int ni = 0; ni < 4; ++ni)
          acc[mi][ni] = __builtin_amdgcn_mfma_f32_16x16x32_f16(af[mi], bf[ni], acc[mi][ni], 0, 0, 0);
    }
  }

#pragma unroll
  for (int mi = 0; mi < 4; ++mi) {
#pragma unroll
    for (int ni = 0; ni < 4; ++ni) {
      floatx4 a4 = acc[mi][ni];
      size_t rowb = m0 + wm * 64 + mi * 16 + q4 * 4;
      size_t col = n0 + wn * 64 + ni * 16 + ln15;
      if (EPI == 5) {
        size_t b = rowb >> 11, l0 = rowb & 2047;
        half4 h = {(_Float16)a4[0], (_Float16)a4[1], (_Float16)a4[2], (_Float16)a4[3]};
        *(half4*)(outh + (((size_t)b * N + col) << 11) + l0) = h;
      } else {
#pragma unroll
        for (int r = 0; r < 4; ++r) {
          size_t idx = (rowb + r) * (size_t)N + col;
          float v = a4[r];
          if (EPI == 1) {
            outf[idx] = v + bias[col] + res[idx];
          } else if (EPI == 2) {
            float ge = 0.5f * v * (1.0f + erff(v * 0.70710678118654752f));
            outh[idx] = (_Float16)ge;
          } else if (EPI == 3) {
            outf[idx] = v + res[idx];
          } else {
            outh[idx] = (_Float16)v;
          }
        }
      }
    }
  }
}

// --------------------- autocorrelation: register radix-8 FFT ---------------
// qk fused transposed layout F[b, ch, l], ch<1024 = q, ch>=1024 = k.
// block = (b, 2 channel-pairs), 256 threads. z = q + i*k; 2048-pt radix-2
// DIF FFT where 3 stages at a time run in registers (thread t holds 8 pts),
// separated by pad-32 conflict-free LDS exchanges. Hermitian split; partial
// spectrum row per block (no atomics), reduced by spec_reduce_kernel.

#define CBFLY(ch, ia, ib, wr, wi) {                      \
    float ax_ = z[ch][ia].x, ay_ = z[ch][ia].y;          \
    float bx_ = z[ch][ib].x, by_ = z[ch][ib].y;          \
    float dx_ = ax_ - bx_, dy_ = ay_ - by_;              \
    z[ch][ia].x = ax_ + bx_; z[ch][ia].y = ay_ + by_;    \
    z[ch][ib].x = dx_ * (wr) - dy_ * (wi);               \
    z[ch][ib].y = dx_ * (wi) + dy_ * (wr); }
#define BFLY2(ia, ib, m) { float2 w_ = twl[ZP32(m)];     \
    CBFLY(0, ia, ib, w_.x, w_.y) CBFLY(1, ia, ib, w_.x, w_.y) }

__global__ __launch_bounds__(256) void corr_fft_kernel(const _Float16* __restrict__ F,
                                                       float* __restrict__ S) {
  __shared__ float2 Zs[2][2112];   // 2048 + pad every 32
  __shared__ float2 twl[1056];     // 1024 twiddles, padded
  int tid = threadIdx.x;
  int b = blockIdx.x >> 9;
  int c0 = (blockIdx.x & 511) << 1;
  const _Float16* qb = F + ((size_t)(b * 2048 + c0) << 11);
  const _Float16* kb = F + ((size_t)(b * 2048 + 1024 + c0) << 11);

  // load 8 points per channel per thread: positions t + 256*j
  float2 z[2][8];
#pragma unroll
  for (int j = 0; j < 8; ++j) {
    int p = tid + 256 * j;
    z[0][j] = make_float2((float)qb[p], (float)kb[p]);
    z[1][j] = make_float2((float)qb[2048 + p], (float)kb[2048 + p]);
  }
  // twiddle table: twl[m] = exp(-2*pi*i*m/2048)
  for (int m = tid; m < 1024; m += 256) {
    float sn, cs;
    __sincosf(-PI_F * (float)m / 1024.0f, &sn, &cs);
    twl[ZP32(m)] = make_float2(cs, sn);
  }
  __syncthreads();

  // ---- round 1: stages sh=10,9,8  (positions t + 256j) ----
  BFLY2(0, 4, tid)
  BFLY2(1, 5, tid + 256)
  BFLY2(2, 6, tid + 512)
  BFLY2(3, 7, tid + 768)
  { float2 wA = twl[ZP32(tid << 1)], wB = twl[ZP32((tid + 256) << 1)];
    CBFLY(0, 0, 2, wA.x, wA.y) CBFLY(1, 0, 2, wA.x, wA.y)
    CBFLY(0, 1, 3, wB.x, wB.y) CBFLY(1, 1, 3, wB.x, wB.y)
    CBFLY(0, 4, 6, wA.x, wA.y) CBFLY(1, 4, 6, wA.x, wA.y)
    CBFLY(0, 5, 7, wB.x, wB.y) CBFLY(1, 5, 7, wB.x, wB.y) }
  { float2 wA = twl[ZP32(tid << 2)];
    CBFLY(0, 0, 1, wA.x, wA.y) CBFLY(1, 0, 1, wA.x, wA.y)
    CBFLY(0, 2, 3, wA.x, wA.y) CBFLY(1, 2, 3, wA.x, wA.y)
    CBFLY(0, 4, 5, wA.x, wA.y) CBFLY(1, 4, 5, wA.x, wA.y)
    CBFLY(0, 6, 7, wA.x, wA.y) CBFLY(1, 6, 7, wA.x, wA.y) }

  // ---- exchange 1: write t+256j, read (t>>5)*256 + (t&31) + 32j ----
#pragma unroll
  for (int j = 0; j < 8; ++j) {
    int p = tid + 256 * j;
    Zs[0][ZP32(p)] = z[0][j];
    Zs[1][ZP32(p)] = z[1][j];
  }
  __syncthreads();
  int t5 = tid & 31, hi1 = (tid >> 5) << 8;
#pragma unroll
  for (int j = 0; j < 8; ++j) {
    int p = hi1 + t5 + 32 * j;
    z[0][j] = Zs[0][ZP32(p)];
    z[1][j] = Zs[1][ZP32(p)];
  }

  // ---- round 2: stages sh=7,6,5 ----
  BFLY2(0, 4, t5 << 3)
  BFLY2(1, 5, (t5 + 32) << 3)
  BFLY2(2, 6, (t5 + 64) << 3)
  BFLY2(3, 7, (t5 + 96) << 3)
  { float2 wA = twl[ZP32(t5 << 4)], wB = twl[ZP32((t5 + 32) << 4)];
    CBFLY(0, 0, 2, wA.x, wA.y) CBFLY(1, 0, 2, wA.x, wA.y)
    CBFLY(0, 1, 3, wB.x, wB.y) CBFLY(1, 1, 3, wB.x, wB.y)
    CBFLY(0, 4, 6, wA.x, wA.y) CBFLY(1, 4, 6, wA.x, wA.y)
    CBFLY(0, 5, 7, wB.x, wB.y) CBFLY(1, 5, 7, wB.x, wB.y) }
  { float2 wA = twl[ZP32(t5 << 5)];
    CBFLY(0, 0, 1, wA.x, wA.y) CBFLY(1, 0, 1, wA.x, wA.y)
    CBFLY(0, 2, 3, wA.x, wA.y) CBFLY(1, 2, 3, wA.x, wA.y)
    CBFLY(0, 4, 5, wA.x, wA.y) CBFLY(1, 4, 5, wA.x, wA.y)
    CBFLY(0, 6, 7, wA.x, wA.y) CBFLY(1, 6, 7, wA.x, wA.y) }

  // ---- exchange 2: write back same slots, read (t>>2)*32 + (t&3) + 4j ----
  // (each slot was read only by this thread -> no barrier before write)
#pragma unroll
  for (int j = 0; j < 8; ++j) {
    int p = hi1 + t5 + 32 * j;
    Zs[0][ZP32(p)] = z[0][j];
    Zs[1][ZP32(p)] = z[1][j];
  }
  __syncthreads();
  int t3 = tid & 3, hi2 = (tid >> 2) << 5;
#pragma unroll
  for (int j = 0; j < 8; ++j) {
    int p = hi2 + t3 + 4 * j;
    z[0][j] = Zs[0][ZP32(p)];
    z[1][j] = Zs[1][ZP32(p)];
  }

  // ---- round 3: stages sh=4,3,2 ----
  BFLY2(0, 4, t3 << 6)
  BFLY2(1, 5, (t3 + 4) << 6)
  BFLY2(2, 6, (t3 + 8) << 6)
  BFLY2(3, 7, (t3 + 12) << 6)
  { float2 wA = twl[ZP32(t3 << 7)], wB = twl[ZP32((t3 + 4) << 7)];
    CBFLY(0, 0, 2, wA.x, wA.y) CBFLY(1, 0, 2, wA.x, wA.y)
    CBFLY(0, 1, 3, wB.x, wB.y) CBFLY(1, 1, 3, wB.x, wB.y)
    CBFLY(0, 4, 6, wA.x, wA.y) CBFLY(1, 4, 6, wA.x, wA.y)
    CBFLY(0, 5, 7, wB.x, wB.y) CBFLY(1, 5, 7, wB.x, wB.y) }
  { float2 wA = twl[ZP32(t3 << 8)];
    CBFLY(0, 0, 1, wA.x, wA.y) CBFLY(1, 0, 1, wA.x, wA.y)
    CBFLY(0, 2, 3, wA.x, wA.y) CBFLY(1, 2, 3, wA.x, wA.y)
    CBFLY(0, 4, 5, wA.x, wA.y) CBFLY(1, 4, 5, wA.x, wA.y)
    CBFLY(0, 6, 7, wA.x, wA.y) CBFLY(1, 6, 7, wA.x, wA.y) }

  // ---- exchange 3: write back same slots, read 8t + j ----
#pragma unroll
  for (int j = 0; j < 8; ++j) {
    int p = hi2 + t3 + 4 * j;
    Zs[0][ZP32(p)] = z[0][j];
    Zs[1][ZP32(p)] = z[1][j];
  }
  __syncthreads();
#pragma unroll
  for (int j = 0; j < 8; ++j) {
    int p = (tid << 3) + j;
    z[0][j] = Zs[0][ZP32(p)];
    z[1][j] = Zs[1][ZP32(p)];
  }

  // ---- round 4: stages sh=1 (w = 1 or -i), sh=0 (w = 1) ----
  CBFLY(0, 0, 2, 1.0f, 0.0f) CBFLY(1, 0, 2, 1.0f, 0.0f)
  CBFLY(0, 1, 3, 0.0f, -1.0f) CBFLY(1, 1, 3, 0.0f, -1.0f)
  CBFLY(0, 4, 6, 1.0f, 0.0f) CBFLY(1, 4, 6, 1.0f, 0.0f)
  CBFLY(0, 5, 7, 0.0f, -1.0f) CBFLY(1, 5, 7, 0.0f, -1.0f)
  CBFLY(0, 0, 1, 1.0f, 0.0f) CBFLY(1, 0, 1, 1.0f, 0.0f)
  CBFLY(0, 2, 3, 1.0f, 0.0f) CBFLY(1, 2, 3, 1.0f, 0.0f)
  CBFLY(0, 4, 5, 1.0f, 0.0f) CBFLY(1, 4, 5, 1.0f, 0.0f)
  CBFLY(0, 6, 7, 1.0f, 0.0f) CBFLY(1, 6, 7, 1.0f, 0.0f)

  // ---- final write (same slots as last read) + spectrum ----
#pragma unroll
  for (int j = 0; j < 8; ++j) {
    int p = (tid << 3) + j;
    Zs[0][ZP32(p)] = z[0][j];
    Zs[1][ZP32(p)] = z[1][j];
  }
  __syncthreads();
  float* Sb = S + (size_t)blockIdx.x * 2050;  // row = b*512 + channel-group
  for (int f = tid; f <= 1024; f += 256) {
    int rf = __brev((unsigned)f) >> 21;
    int rmf = __brev((unsigned)((2048 - f) & 2047)) >> 21;
    float pr = 0.f, pim = 0.f;
#pragma unroll
    for (int ch = 0; ch < 2; ++ch) {
      float2 zf = Zs[ch][ZP32(rf)], zm = Zs[ch][ZP32(rmf)];
      float Qr = 0.5f * (zf.x + zm.x), Qi = 0.5f * (zf.y - zm.y);
      float Kr = 0.5f * (zf.y + zm.y), Ki = -0.5f * (zf.x - zm.x);
      pr += Qr * Kr + Qi * Ki;
      pim += Qi * Kr - Qr * Ki;
    }
    Sb[2 * f] = pr;
    Sb[2 * f + 1] = pim;
  }
}

// ------------- reduce 512 partial spectrum rows -> 8-way S8 format ---------
__global__ __launch_bounds__(256) void spec_reduce_kernel(const float* __restrict__ Sbig,
                                                          float* __restrict__ S8) {
  int f = blockIdx.x * 256 + threadIdx.x;  // 0..2303, guard
  int sc = blockIdx.y;                     // 0..7 (64-row chunk)
  int b = blockIdx.z;                      // 0..7
  if (f >= 2050) return;
  const float* src = Sbig + ((size_t)b * 512 + (size_t)sc * 64) * 2050 + f;
  float s = 0.f;
  for (int i = 0; i < 64; ++i) s += src[(size_t)i * 2050];
  S8[((size_t)b * 8 + sc) * 2050 + f] = s;
}

// --------------- per-batch: inverse FFT -> mean_corr -> top-7 + softmax ----
__global__ __launch_bounds__(256) void corr_topk_kernel(const float* __restrict__ S,
                                                        int* __restrict__ delays,
                                                        float* __restrict__ alphas,
                                                        int C, int L) {
  __shared__ float2 W[2048];
  __shared__ float mc[2048];
  __shared__ float rv[4];
  __shared__ int ri[4];
  __shared__ float swv[7];
  __shared__ int sdi[7];
  int b = blockIdx.x, tid = threadIdx.x;
  const float* Sb = S + (size_t)b * 8 * 2050;
  for (int f = tid; f < 2048; f += 256) {
    int ff = f <= 1024 ? f : 2048 - f;
    float re = 0.f, im = 0.f;
    for (int s = 0; s < 8; ++s) {
      re += Sb[s * 2050 + 2 * ff];
      im += Sb[s * 2050 + 2 * ff + 1];
    }
    W[f] = make_float2(re, f <= 1024 ? -im : im);
  }
  __syncthreads();
  for (int sh = 10; sh >= 0; --sh) {
    int s = 1 << sh;
    for (int j = tid; j < 1024; j += 256) {
      int t = j & (s - 1);
      int i0 = ((j >> sh) << (sh + 1)) | t;
      int i1 = i0 + s;
      float2 a = W[i0], bb = W[i1];
      float ang = -PI_F * (float)t / (float)s;
      float sn, cs;
      __sincosf(ang, &sn, &cs);
      float2 d = make_float2(a.x - bb.x, a.y - bb.y);
      W[i0] = make_float2(a.x + bb.x, a.y + bb.y);
      W[i1] = make_float2(d.x * cs - d.y * sn, d.x * sn + d.y * cs);
    }
    __syncthreads();
  }
  float inv = 1.0f / ((float)C * (float)L);
  for (int t = tid; t < 2048; t += 256) mc[t] = W[__brev((unsigned)t) >> 21].x * inv;
  __syncthreads();
  int wv = tid >> 6, lane = tid & 63;
  for (int it = 0; it < 7; ++it) {
    float bvv = -1e30f;
    int bi = 0;
    for (int e = tid * 8; e < tid * 8 + 8; ++e) {
      float v = mc[e];
      if (v > bvv) { bvv = v; bi = e; }
    }
    for (int o = 32; o > 0; o >>= 1) {
      float ov = __shfl_down(bvv, o, 64);
      int oi = __shfl_down(bi, o, 64);
      if (ov > bvv || (ov == bvv && oi < bi)) { bvv = ov; bi = oi; }
    }
    if (lane == 0) { rv[wv] = bvv; ri[wv] = bi; }
    __syncthreads();
    if (tid == 0) {
      float fv = rv[0];
      int fi = ri[0];
      for (int w2 = 1; w2 < 4; ++w2)
        if (rv[w2] > fv || (rv[w2] == fv && ri[w2] < fi)) { fv = rv[w2]; fi = ri[w2]; }
      swv[it] = fv;
      sdi[it] = fi;
      mc[fi] = -1e30f;
    }
    __syncthreads();
  }
  if (tid == 0) {
    float mx = swv[0];
    for (int i = 1; i < 7; ++i) mx = fmaxf(mx, swv[i]);
    float e[7], s = 0.f;
    for (int i = 0; i < 7; ++i) { e[i] = expf(swv[i] - mx); s += e[i]; }
    for (int i = 0; i < 7; ++i) {
      alphas[b * 7 + i] = e[i] / s;
      delays[b * 7 + i] = sdi[i];
    }
  }
}

// ------------------- lag aggregation on xn (commuted past Wv) --------------
__global__ __launch_bounds__(256) void agg_kernel(const _Float16* __restrict__ v,
                                                  const int* __restrict__ delays,
                                                  const float* __restrict__ alphas,
                                                  _Float16* __restrict__ agg,
                                                  int L, int C) {
  int bt = blockIdx.x;
  int b = bt >> 11, t = bt & 2047;
  int tid = threadIdx.x;
  const _Float16* vb = v + (size_t)b * L * C;
  float ax = 0.f, ay = 0.f, az = 0.f, aw = 0.f;
#pragma unroll
  for (int i = 0; i < 7; ++i) {
    int d = delays[b * 7 + i];
    float a = alphas[b * 7 + i];
    int src = t + d;
    if (src >= L) src -= L;
    half4 x = ((const half4*)(vb + (size_t)src * C))[tid];
    ax += a * (float)x.x; ay += a * (float)x.y;
    az += a * (float)x.z; aw += a * (float)x.w;
  }
  half4 h = {(_Float16)ax, (_Float16)ay, (_Float16)az, (_Float16)aw};
  ((half4*)(agg + (size_t)bt * C))[tid] = h;
}

// ----------------- series decomposition: out = x - movavg25(x) -------------
template <int WRITE_H>
__global__ __launch_bounds__(256) void decomp_kernel(const float* __restrict__ xin,
                                                     float* __restrict__ xout,
                                                     _Float16* __restrict__ xh,
                                                     int L, int C) {
  int c = blockIdx.x * 256 + threadIdx.x;
  int t0 = blockIdx.y * 128;
  int b = blockIdx.z;
  const float* xb = xin + (size_t)b * L * C + c;
  float sum = 0.f;
  for (int j = t0 - 12; j <= t0 + 12; ++j) {
    int jc = j < 0 ? 0 : (j > L - 1 ? L - 1 : j);
    sum += xb[(size_t)jc * C];
  }
  for (int t = t0; t < t0 + 128; ++t) {
    float xv = xb[(size_t)t * C];
    float o = xv - sum * (1.0f / 25.0f);
    size_t oidx = ((size_t)b * L + t) * C + c;
    xout[oidx] = o;
    if (WRITE_H) xh[oidx] = (_Float16)o;
    int nj = t + 13; if (nj > L - 1) nj = L - 1;
    int oj = t - 12; if (oj < 0) oj = 0;
    sum += xb[(size_t)nj * C] - xb[(size_t)oj * C];
  }
}

// ------------------------------- launcher ----------------------------------
extern "C" void kernel_launch(void* const* d_in, const int* in_sizes, int n_in,
                              void* d_out, int out_size, void* d_ws, size_t ws_size,
                              hipStream_t stream) {
  const float* x = (const float*)d_in[0];
  const float* Wq = (const float*)d_in[1];
  const float* Wk = (const float*)d_in[2];
  const float* Wv = (const float*)d_in[3];
  const float* Wo = (const float*)d_in[4];
  const float* bo = (const float*)d_in[5];
  const float* lng = (const float*)d_in[6];
  const float* lnb = (const float*)d_in[7];
  const float* W1 = (const float*)d_in[8];
  const float* W2 = (const float*)d_in[9];
  float* out = (float*)d_out;

  const int B = 8, L = 2048, C = 1024, HD = 4096;
  const int M = B * L;  // 16384

  char* ws = (char*)d_ws;
  size_t off = 0;
  auto alloc = [&](size_t bytes) -> void* {
    void* p = ws + off;
    off = (off + bytes + 255) & ~(size_t)255;
    return p;
  };
  // ~150.6 MiB total (under the 152.1 MiB proven previously)
  _Float16* wqkh = (_Float16*)alloc((size_t)2 * C * C * 2); // 4 MB (q rows, then k rows)
  _Float16* wvoh = (_Float16*)alloc((size_t)C * C * 2);     // 2 MB (Wo*Wv)
  _Float16* w1h = (_Float16*)alloc((size_t)HD * C * 2);     // 8 MB
  _Float16* w2h = (_Float16*)alloc((size_t)C * HD * 2);     // 8 MB
  float* S8 = (float*)alloc((size_t)B * 8 * 2050 * 4);      // 512 KB (reduced spectrum)
  int* dl = (int*)alloc(B * 7 * 4);
  float* al = (float*)alloc(B * 7 * 4);
  _Float16* xn = (_Float16*)alloc((size_t)M * C * 2);       // 32 MB; later x2h
  _Float16* qkh = (_Float16*)alloc((size_t)M * 2 * C * 2);  // 64 MB [B,2C,L]; later x1/x3
  _Float16* vh = (_Float16*)alloc((size_t)4096 * 2050 * 4); // 33.6 MB: Sbig/wvT/woh, aggh, hid
  (void)ws_size; (void)in_sizes; (void)n_in; (void)out_size;

  _Float16* wvT = vh;                        // setup-only (dead before corr_fft)
  _Float16* woh = vh + (size_t)C * C;        // setup-only (dead before corr_fft)
  float* Sbig = (float*)vh;       // partial spectra (steps 6-7), dead before agg
  _Float16* aggh = vh;            // agg of xn (from step 8)
  float* x1 = (float*)qkh;        // q,k dead after corr_fft (64 MB)
  _Float16* x2h = xn;             // xn dead after agg
  float* x2 = out;                // d_out doubles as x2 scratch
  float* x3 = (float*)qkh;        // x1 dead after decomp1
  _Float16* hidc = vh;            // Sbig/aggh dead after attn GEMM (32 MB slice)

  // 1. weights -> fp16 (+ Wv transpose)
  cvt_f16_kernel<<<(C * C / 4 + 255) / 256, 256, 0, stream>>>(Wq, wqkh, C * C / 4);
  cvt_f16_kernel<<<(C * C / 4 + 255) / 256, 256, 0, stream>>>(Wk, wqkh + (size_t)C * C, C * C / 4);
  cvt_f16_kernel<<<(C * C / 4 + 255) / 256, 256, 0, stream>>>(Wo, woh, C * C / 4);
  transpose_f16_kernel<<<dim3(16, 16), 256, 0, stream>>>(Wv, wvT, C);
  cvt_f16_kernel<<<(HD * C / 4 + 255) / 256, 256, 0, stream>>>(W1, w1h, HD * C / 4);
  cvt_f16_kernel<<<(HD * C / 4 + 255) / 256, 256, 0, stream>>>(W2, w2h, HD * C / 4);
  // 2. Wvo[o,c] = sum_j Wo[o,j]*Wv[j,c]
  gemm_kernel<4><<<dim3(8, 8), 256, 0, stream>>>(woh, wvT, C, C, C, C, C,
                                                 nullptr, wvoh, nullptr, nullptr);
  // 3. LayerNorm -> fp16
  ln_kernel<<<M, 256, 0, stream>>>(x, lng, lnb, xn, C);
  // 4. fused q,k GEMM -> transposed [B, 2C, L]
  gemm_kernel<5><<<dim3(M / 128, 2 * C / 128), 256, 0, stream>>>(
      xn, wqkh, M, 2 * C, C, C, C, nullptr, qkh, nullptr, nullptr);
  // 5. channel FFTs -> per-block partial spectrum rows (no atomics)
  corr_fft_kernel<<<B * (C / 2), 256, 0, stream>>>(qkh, Sbig);
  // 6. reduce 512 partial rows -> 8-way S8
  spec_reduce_kernel<<<dim3(9, 8, 8), 256, 0, stream>>>(Sbig, S8);
  // 7. inverse FFT + top-7 + softmax
  corr_topk_kernel<<<B, 256, 0, stream>>>(S8, dl, al, C, L);
  // 8. lag aggregation on xn (commuted) -> aggh
  agg_kernel<<<B * L, 256, 0, stream>>>(xn, dl, al, aggh, L, C);
  // 9. attn = aggh * Wvo^T + bo + x -> x1 (fp32)
  gemm_kernel<1><<<dim3(M / 128, C / 128), 256, 0, stream>>>(
      aggh, wvoh, M, C, C, C, C, x1, nullptr, bo, x);
  // 10. decomp1: x2 = x1 - movavg(x1) -> d_out + fp16 copy (xn region)
  decomp_kernel<1><<<dim3(C / 256, L / 128, B), 256, 0, stream>>>(x1, x2, x2h, L, C);
  // 11. FFN: N-sliced FFN1, K-partial FFN2 (1024-block dispatches)
  for (int ci = 0; ci < 4; ++ci) {
    gemm_kernel<2><<<dim3(M / 128, 8), 256, 0, stream>>>(
        x2h, w1h + (size_t)ci * 1024 * C, M, 1024, C, C, C,
        nullptr, hidc, nullptr, nullptr);
    gemm_kernel<3><<<dim3(M / 128, C / 128), 256, 0, stream>>>(
        hidc, w2h + (size_t)ci * 1024, M, C, 1024, 1024, HD,
        x3, nullptr, nullptr, ci == 0 ? x2 : x3);
  }
  // 12. decomp2 -> out
  decomp_kernel<0><<<dim3(C / 256, L / 128, B), 256, 0, stream>>>(x3, out, nullptr, L, C);
}

// Round 2
// 955.856 us; speedup vs baseline: 1.2749x; 1.1969x over previous
//
#include <hip/hip_runtime.h>
#include <cstdint>
#include <cstddef>

// ---------------------------------------------------------------------------
// AutoformerEncodeBlock R7:
//  - GEMM rewritten as 256x256/BK=64 8-wave pipelined kernel (T2+T3+T4+T5):
//    2-K-tile LDS dbuf (128 KiB), chunked global_load_lds staged one K-tile
//    ahead (2 loads/phase), counted vmcnt(2)/vmcnt(4) waits (never 0 in main
//    loop), raw s_barrier x2/K-tile, XOR-granule swizzle (inverse-swizzled
//    global source + swizzled ds_read), setprio around MFMA, XCD swizzle.
//  - corr_fft: register radix-8 FFT (R6)
//  - v-GEMM eliminated via Wvo = Wo*Wv fold; q,k fused GEMM; FFN sliced.
// ---------------------------------------------------------------------------

typedef _Float16 half8 __attribute__((ext_vector_type(8)));
typedef _Float16 half4 __attribute__((ext_vector_type(4)));
typedef float floatx4 __attribute__((ext_vector_type(4)));

#define PI_F 3.14159265358979323846f
#define ZP32(i) ((i) + ((i) >> 5))  // pad every 32 float2 elements

__device__ __forceinline__ void load_lds16(const void* g, void* l) {
  __builtin_amdgcn_global_load_lds((__attribute__((address_space(1))) void*)g,
                                   (__attribute__((address_space(3))) void*)l,
                                   16, 0, 0);
}

// ---------------------------- small utility kernels ------------------------

__global__ __launch_bounds__(256) void cvt_f16_kernel(const float* __restrict__ src,
                                                      _Float16* __restrict__ dst, int n4) {
  int i = blockIdx.x * 256 + threadIdx.x;
  if (i >= n4) return;
  float4 v = ((const float4*)src)[i];
  half4 h = {(_Float16)v.x, (_Float16)v.y, (_Float16)v.z, (_Float16)v.w};
  ((half4*)dst)[i] = h;
}

// dst[c, j] = src[j, c]  (n x n, fp32 -> fp16), 64x64 LDS tiles
__global__ __launch_bounds__(256) void transpose_f16_kernel(const float* __restrict__ src,
                                                            _Float16* __restrict__ dst, int n) {
  __shared__ float tile[64][65];
  int j0 = blockIdx.y * 64, c0 = blockIdx.x * 64;
  int tr = threadIdx.x >> 4;
  int tc = threadIdx.x & 15;
#pragma unroll
  for (int rr = 0; rr < 64; rr += 16) {
    float4 v = *(const float4*)(src + (size_t)(j0 + tr + rr) * n + c0 + tc * 4);
    tile[tr + rr][tc * 4 + 0] = v.x;
    tile[tr + rr][tc * 4 + 1] = v.y;
    tile[tr + rr][tc * 4 + 2] = v.z;
    tile[tr + rr][tc * 4 + 3] = v.w;
  }
  __syncthreads();
#pragma unroll
  for (int rr = 0; rr < 64; rr += 16) {
    int c = tr + rr;
    half4 h = {(_Float16)tile[tc * 4 + 0][c], (_Float16)tile[tc * 4 + 1][c],
               (_Float16)tile[tc * 4 + 2][c], (_Float16)tile[tc * 4 + 3][c]};
    *(half4*)(dst + (size_t)(c0 + c) * n + j0 + tc * 4) = h;
  }
}

// --------------------------------- LayerNorm -------------------------------
__global__ __launch_bounds__(256) void ln_kernel(const float* __restrict__ x,
                                                 const float* __restrict__ g,
                                                 const float* __restrict__ b,
                                                 _Float16* __restrict__ xn, int C) {
  int row = blockIdx.x;
  int t = threadIdx.x;
  const float4* xr = (const float4*)(x + (size_t)row * C);
  float4 v = xr[t];
  float s = v.x + v.y + v.z + v.w;
  float s2 = v.x * v.x + v.y * v.y + v.z * v.z + v.w * v.w;
  for (int o = 32; o > 0; o >>= 1) {
    s += __shfl_down(s, o, 64);
    s2 += __shfl_down(s2, o, 64);
  }
  __shared__ float red[8];
  int wave = t >> 6, lane = t & 63;
  if (lane == 0) { red[wave] = s; red[4 + wave] = s2; }
  __syncthreads();
  __shared__ float stats[2];
  if (t == 0) {
    float ts = red[0] + red[1] + red[2] + red[3];
    float ts2 = red[4] + red[5] + red[6] + red[7];
    float mu = ts / (float)C;
    float var = ts2 / (float)C - mu * mu;
    stats[0] = mu;
    stats[1] = 1.0f / sqrtf(var + 1e-5f);
  }
  __syncthreads();
  float mu = stats[0], rs = stats[1];
  float4 gv = ((const float4*)g)[t];
  float4 bv = ((const float4*)b)[t];
  half4 h = {(_Float16)((v.x - mu) * rs * gv.x + bv.x),
             (_Float16)((v.y - mu) * rs * gv.y + bv.y),
             (_Float16)((v.z - mu) * rs * gv.z + bv.z),
             (_Float16)((v.w - mu) * rs * gv.w + bv.w)};
  ((half4*)(xn + (size_t)row * C))[t] = h;
}

// ----------------------------------- GEMM ----------------------------------
// C[M,N] = A[M,K] * Bw[N,K]^T (fp16). 256x256 tile, BK=64, 8 waves (2x4),
// per-wave 128x64 output (acc[8][4]). 2-K-tile LDS double buffer; staging one
// K-tile ahead as 8 chunks/K-tile (order B0,B1,B2,B3,A0,A2,A1,A3; 2 per
// phase); counted vmcnt waits: phase0 vmcnt(2) covers B*+A0/A2, phase2
// vmcnt(4) covers A1/A3. XOR-granule swizzle: global source pre-swizzled
// (lane granule = l7^l3), ds_read applies granule^(row&7).
// EPI: 1 = +bias[col]+res fp32, 2 = GELU -> fp16, 3 = +res fp32 (RMW ok),
//      4 = plain fp16, 5 = fp16 transposed [B, N, L] (L=2048)
template <int EPI>
__global__ __launch_bounds__(512, 2) void gemm256_kernel(
    const _Float16* __restrict__ A, const _Float16* __restrict__ Bw,
    int M, int N, int K, int lda, int ldb,
    float* __restrict__ outf, _Float16* __restrict__ outh,
    const float* __restrict__ bias, const float* __restrict__ res) {
  __shared__ _Float16 lds[2][2][256 * 64];  // [buf][A=0/B=1][256 rows x 64 halfs]

  int tid = threadIdx.x;
  int lane = tid & 63;
  int wave = tid >> 6;          // 0..7
  int wm = wave >> 2;           // 0..1  (M half)
  int wn = wave & 3;            // 0..3  (N quarter)
  int ln15 = lane & 15, q4 = lane >> 4;
  int l3 = lane >> 3, l7 = lane & 7;

  int nwg = gridDim.x, orig = blockIdx.x;
  int wg = ((nwg & 7) == 0) ? ((orig & 7) * (nwg >> 3) + (orig >> 3)) : orig;
  int nbn = N >> 8;
  size_t m0 = (size_t)(wg / nbn) << 8;
  size_t n0 = (size_t)(wg % nbn) << 8;

  // swizzled ds_read granule offsets (halfs): granule g read at slot g^(row&7),
  // row&7 == lane&7 for all fragment reads.
  int sg0 = (q4 ^ l7) << 3;         // kk=0
  int sg1 = ((q4 + 4) ^ l7) << 3;   // kk=32

  floatx4 acc[8][4] = {};

  // staging: lane covers row (8*wave + l3) of each 64-row chunk, global
  // granule pre-swizzled to l7^l3 so linear LDS dest == swizzled layout.
  const _Float16* srcA = A + (m0 + 8 * wave + l3) * (size_t)lda + (size_t)((l7 ^ l3) * 8);
  const _Float16* srcB = Bw + (n0 + 8 * wave + l3) * (size_t)ldb + (size_t)((l7 ^ l3) * 8);
  char* ldsA0 = (char*)&lds[0][0][0] + wave * 1024;
  char* ldsB0 = (char*)&lds[0][1][0] + wave * 1024;

  // prologue: stage tile 0 (order B0,B1,B2,B3,A0,A2,A1,A3) into buf 0
  load_lds16(srcB, ldsB0);
  load_lds16(srcB + (size_t)64 * ldb, ldsB0 + 1 * 8192);
  load_lds16(srcB + (size_t)128 * ldb, ldsB0 + 2 * 8192);
  load_lds16(srcB + (size_t)192 * ldb, ldsB0 + 3 * 8192);
  load_lds16(srcA, ldsA0);
  load_lds16(srcA + (size_t)128 * lda, ldsA0 + 2 * 8192);
  load_lds16(srcA + (size_t)64 * lda, ldsA0 + 1 * 8192);
  load_lds16(srcA + (size_t)192 * lda, ldsA0 + 3 * 8192);

  int nk = K >> 6;
  half8 bf[4][2], aA[2][2];

#define RD_B() _Pragma("unroll") for (int ni = 0; ni < 4; ++ni) {      \
    const _Float16* p_ = cB + ((wn * 64 + ni * 16 + ln15) << 6);       \
    bf[ni][0] = *(const half8*)(p_ + sg0);                             \
    bf[ni][1] = *(const half8*)(p_ + sg1); }
#define RD_A(mi) { const _Float16* p_ = cA + ((wm * 128 + (mi) * 16 + ln15) << 6); \
    aA[(mi) & 1][0] = *(const half8*)(p_ + sg0);                                   \
    aA[(mi) & 1][1] = *(const half8*)(p_ + sg1); }
#define MM(mi) _Pragma("unroll") for (int ni = 0; ni < 4; ++ni) {      \
    acc[mi][ni] = __builtin_amdgcn_mfma_f32_16x16x32_f16(aA[(mi) & 1][0], bf[ni][0], acc[mi][ni], 0, 0, 0); \
    acc[mi][ni] = __builtin_amdgcn_mfma_f32_16x16x32_f16(aA[(mi) & 1][1], bf[ni][1], acc[mi][ni], 0, 0, 0); }

  for (int t = 0; t < nk; ++t) {
    int cur = t & 1;
    const _Float16* cA = &lds[cur][0][0];
    const _Float16* cB = &lds[cur][1][0];
    const _Float16* As = srcA + (size_t)(t + 1) * 64;
    const _Float16* Bs = srcB + (size_t)(t + 1) * 64;
    char* stA = ldsA0 + (cur ^ 1) * 65536;
    char* stB = ldsB0 + (cur ^ 1) * 65536;
    bool pf = (t + 1 < nk);

    // ---- phase 0: needs B_wn (pos<=4) + A(2wm) (pos 5/6) -> vmcnt(2) ----
    __builtin_amdgcn_sched_barrier(0);
    asm volatile("s_waitcnt vmcnt(2)" ::: "memory");
    __builtin_amdgcn_s_barrier();
    __builtin_amdgcn_sched_barrier(0);
    if (pf) {
      load_lds16(Bs, stB);
      load_lds16(Bs + (size_t)64 * ldb, stB + 1 * 8192);
    }
    RD_B();
    RD_A(0); RD_A(1);
    __builtin_amdgcn_s_setprio(1);
    MM(0); MM(1);
    __builtin_amdgcn_s_setprio(0);
    __builtin_amdgcn_sched_barrier(0);
    // ---- phase 1 ----
    if (pf) {
      load_lds16(Bs + (size_t)128 * ldb, stB + 2 * 8192);
      load_lds16(Bs + (size_t)192 * ldb, stB + 3 * 8192);
    }
    RD_A(2); RD_A(3);
    __builtin_amdgcn_s_setprio(1);
    MM(2); MM(3);
    __builtin_amdgcn_s_setprio(0);
    __builtin_amdgcn_sched_barrier(0);
    // ---- phase 2: needs A(2wm+1) (pos 7/8) -> vmcnt(4); last tile: 0 ----
    if (pf) {
      asm volatile("s_waitcnt vmcnt(4)" ::: "memory");
    } else {
      asm volatile("s_waitcnt vmcnt(0)" ::: "memory");
    }
    __builtin_amdgcn_s_barrier();
    __builtin_amdgcn_sched_barrier(0);
    if (pf) {
      load_lds16(As, stA);
      load_lds16(As + (size_t)128 * lda, stA + 2 * 8192);
    }
    RD_A(4); RD_A(5);
    __builtin_amdgcn_s_setprio(1);
    MM(4); MM(5);
    __builtin_amdgcn_s_setprio(0);
    __builtin_amdgcn_sched_barrier(0);
    // ---- phase 3 ----
    if (pf) {
      load_lds16(As + (size_t)64 * lda, stA + 1 * 8192);
      load_lds16(As + (size_t)192 * lda, stA + 3 * 8192);
    }
    RD_A(6); RD_A(7);
    __builtin_amdgcn_s_setprio(1);
    MM(6); MM(7);
    __builtin_amdgcn_s_setprio(0);
    __builtin_amdgcn_sched_barrier(0);
  }
#undef RD_B
#undef RD_A
#undef MM

#pragma unroll
  for (int mi = 0; mi < 8; ++mi) {
#pragma unroll
    for (int ni = 0; ni < 4; ++ni) {
      floatx4 a4 = acc[mi][ni];
      size_t rowb = m0 + wm * 128 + mi * 16 + q4 * 4;
      size_t col = n0 + wn * 64 + ni * 16 + ln15;
      if (EPI == 5) {
        size_t b = rowb >> 11, l0 = rowb & 2047;
        half4 h = {(_Float16)a4[0], (_Float16)a4[1], (_Float16)a4[2], (_Float16)a4[3]};
        *(half4*)(outh + (((size_t)b * N + col) << 11) + l0) = h;
      } else {
#pragma unroll
        for (int r = 0; r < 4; ++r) {
          size_t idx = (rowb + r) * (size_t)N + col;
          float v = a4[r];
          if (EPI == 1) {
            outf[idx] = v + bias[col] + res[idx];
          } else if (EPI == 2) {
            float ge = 0.5f * v * (1.0f + erff(v * 0.70710678118654752f));
            outh[idx] = (_Float16)ge;
          } else if (EPI == 3) {
            outf[idx] = v + res[idx];
          } else {
            outh[idx] = (_Float16)v;
          }
        }
      }
    }
  }
}

// --------------------- autocorrelation: register radix-8 FFT ---------------
// qk fused transposed layout F[b, ch, l], ch<1024 = q, ch>=1024 = k.
// block = (b, 2 channel-pairs), 256 threads. z = q + i*k; 2048-pt radix-2
// DIF FFT where 3 stages at a time run in registers (thread t holds 8 pts),
// separated by pad-32 conflict-free LDS exchanges. Hermitian split; partial
// spectrum row per block (no atomics), reduced by spec_reduce_kernel.

#define CBFLY(ch, ia, ib, wr, wi) {                      \
    float ax_ = z[ch][ia].x, ay_ = z[ch][ia].y;          \
    float bx_ = z[ch][ib].x, by_ = z[ch][ib].y;          \
    float dx_ = ax_ - bx_, dy_ = ay_ - by_;              \
    z[ch][ia].x = ax_ + bx_; z[ch][ia].y = ay_ + by_;    \
    z[ch][ib].x = dx_ * (wr) - dy_ * (wi);               \
    z[ch][ib].y = dx_ * (wi) + dy_ * (wr); }
#define BFLY2(ia, ib, m) { float2 w_ = twl[ZP32(m)];     \
    CBFLY(0, ia, ib, w_.x, w_.y) CBFLY(1, ia, ib, w_.x, w_.y) }

__global__ __launch_bounds__(256) void corr_fft_kernel(const _Float16* __restrict__ F,
                                                       float* __restrict__ S) {
  __shared__ float2 Zs[2][2112];   // 2048 + pad every 32
  __shared__ float2 twl[1056];     // 1024 twiddles, padded
  int tid = threadIdx.x;
  int b = blockIdx.x >> 9;
  int c0 = (blockIdx.x & 511) << 1;
  const _Float16* qb = F + ((size_t)(b * 2048 + c0) << 11);
  const _Float16* kb = F + ((size_t)(b * 2048 + 1024 + c0) << 11);

  // load 8 points per channel per thread: positions t + 256*j
  float2 z[2][8];
#pragma unroll
  for (int j = 0; j < 8; ++j) {
    int p = tid + 256 * j;
    z[0][j] = make_float2((float)qb[p], (float)kb[p]);
    z[1][j] = make_float2((float)qb[2048 + p], (float)kb[2048 + p]);
  }
  // twiddle table: twl[m] = exp(-2*pi*i*m/2048)
  for (int m = tid; m < 1024; m += 256) {
    float sn, cs;
    __sincosf(-PI_F * (float)m / 1024.0f, &sn, &cs);
    twl[ZP32(m)] = make_float2(cs, sn);
  }
  __syncthreads();

  // ---- round 1: stages sh=10,9,8  (positions t + 256j) ----
  BFLY2(0, 4, tid)
  BFLY2(1, 5, tid + 256)
  BFLY2(2, 6, tid + 512)
  BFLY2(3, 7, tid + 768)
  { float2 wA = twl[ZP32(tid << 1)], wB = twl[ZP32((tid + 256) << 1)];
    CBFLY(0, 0, 2, wA.x, wA.y) CBFLY(1, 0, 2, wA.x, wA.y)
    CBFLY(0, 1, 3, wB.x, wB.y) CBFLY(1, 1, 3, wB.x, wB.y)
    CBFLY(0, 4, 6, wA.x, wA.y) CBFLY(1, 4, 6, wA.x, wA.y)
    CBFLY(0, 5, 7, wB.x, wB.y) CBFLY(1, 5, 7, wB.x, wB.y) }
  { float2 wA = twl[ZP32(tid << 2)];
    CBFLY(0, 0, 1, wA.x, wA.y) CBFLY(1, 0, 1, wA.x, wA.y)
    CBFLY(0, 2, 3, wA.x, wA.y) CBFLY(1, 2, 3, wA.x, wA.y)
    CBFLY(0, 4, 5, wA.x, wA.y) CBFLY(1, 4, 5, wA.x, wA.y)
    CBFLY(0, 6, 7, wA.x, wA.y) CBFLY(1, 6, 7, wA.x, wA.y) }

  // ---- exchange 1: write t+256j, read (t>>5)*256 + (t&31) + 32j ----
#pragma unroll
  for (int j = 0; j < 8; ++j) {
    int p = tid + 256 * j;
    Zs[0][ZP32(p)] = z[0][j];
    Zs[1][ZP32(p)] = z[1][j];
  }
  __syncthreads();
  int t5 = tid & 31, hi1 = (tid >> 5) << 8;
#pragma unroll
  for (int j = 0; j < 8; ++j) {
    int p = hi1 + t5 + 32 * j;
    z[0][j] = Zs[0][ZP32(p)];
    z[1][j] = Zs[1][ZP32(p)];
  }

  // ---- round 2: stages sh=7,6,5 ----
  BFLY2(0, 4, t5 << 3)
  BFLY2(1, 5, (t5 + 32) << 3)
  BFLY2(2, 6, (t5 + 64) << 3)
  BFLY2(3, 7, (t5 + 96) << 3)
  { float2 wA = twl[ZP32(t5 << 4)], wB = twl[ZP32((t5 + 32) << 4)];
    CBFLY(0, 0, 2, wA.x, wA.y) CBFLY(1, 0, 2, wA.x, wA.y)
    CBFLY(0, 1, 3, wB.x, wB.y) CBFLY(1, 1, 3, wB.x, wB.y)
    CBFLY(0, 4, 6, wA.x, wA.y) CBFLY(1, 4, 6, wA.x, wA.y)
    CBFLY(0, 5, 7, wB.x, wB.y) CBFLY(1, 5, 7, wB.x, wB.y) }
  { float2 wA = twl[ZP32(t5 << 5)];
    CBFLY(0, 0, 1, wA.x, wA.y) CBFLY(1, 0, 1, wA.x, wA.y)
    CBFLY(0, 2, 3, wA.x, wA.y) CBFLY(1, 2, 3, wA.x, wA.y)
    CBFLY(0, 4, 5, wA.x, wA.y) CBFLY(1, 4, 5, wA.x, wA.y)
    CBFLY(0, 6, 7, wA.x, wA.y) CBFLY(1, 6, 7, wA.x, wA.y) }

  // ---- exchange 2: write back same slots, read (t>>2)*32 + (t&3) + 4j ----
  // (each slot was read only by this thread -> no barrier before write)
#pragma unroll
  for (int j = 0; j < 8; ++j) {
    int p = hi1 + t5 + 32 * j;
    Zs[0][ZP32(p)] = z[0][j];
    Zs[1][ZP32(p)] = z[1][j];
  }
  __syncthreads();
  int t3 = tid & 3, hi2 = (tid >> 2) << 5;
#pragma unroll
  for (int j = 0; j < 8; ++j) {
    int p = hi2 + t3 + 4 * j;
    z[0][j] = Zs[0][ZP32(p)];
    z[1][j] = Zs[1][ZP32(p)];
  }

  // ---- round 3: stages sh=4,3,2 ----
  BFLY2(0, 4, t3 << 6)
  BFLY2(1, 5, (t3 + 4) << 6)
  BFLY2(2, 6, (t3 + 8) << 6)
  BFLY2(3, 7, (t3 + 12) << 6)
  { float2 wA = twl[ZP32(t3 << 7)], wB = twl[ZP32((t3 + 4) << 7)];
    CBFLY(0, 0, 2, wA.x, wA.y) CBFLY(1, 0, 2, wA.x, wA.y)
    CBFLY(0, 1, 3, wB.x, wB.y) CBFLY(1, 1, 3, wB.x, wB.y)
    CBFLY(0, 4, 6, wA.x, wA.y) CBFLY(1, 4, 6, wA.x, wA.y)
    CBFLY(0, 5, 7, wB.x, wB.y) CBFLY(1, 5, 7, wB.x, wB.y) }
  { float2 wA = twl[ZP32(t3 << 8)];
    CBFLY(0, 0, 1, wA.x, wA.y) CBFLY(1, 0, 1, wA.x, wA.y)
    CBFLY(0, 2, 3, wA.x, wA.y) CBFLY(1, 2, 3, wA.x, wA.y)
    CBFLY(0, 4, 5, wA.x, wA.y) CBFLY(1, 4, 5, wA.x, wA.y)
    CBFLY(0, 6, 7, wA.x, wA.y) CBFLY(1, 6, 7, wA.x, wA.y) }

  // ---- exchange 3: write back same slots, read 8t + j ----
#pragma unroll
  for (int j = 0; j < 8; ++j) {
    int p = hi2 + t3 + 4 * j;
    Zs[0][ZP32(p)] = z[0][j];
    Zs[1][ZP32(p)] = z[1][j];
  }
  __syncthreads();
#pragma unroll
  for (int j = 0; j < 8; ++j) {
    int p = (tid << 3) + j;
    z[0][j] = Zs[0][ZP32(p)];
    z[1][j] = Zs[1][ZP32(p)];
  }

  // ---- round 4: stages sh=1 (w = 1 or -i), sh=0 (w = 1) ----
  CBFLY(0, 0, 2, 1.0f, 0.0f) CBFLY(1, 0, 2, 1.0f, 0.0f)
  CBFLY(0, 1, 3, 0.0f, -1.0f) CBFLY(1, 1, 3, 0.0f, -1.0f)
  CBFLY(0, 4, 6, 1.0f, 0.0f) CBFLY(1, 4, 6, 1.0f, 0.0f)
  CBFLY(0, 5, 7, 0.0f, -1.0f) CBFLY(1, 5, 7, 0.0f, -1.0f)
  CBFLY(0, 0, 1, 1.0f, 0.0f) CBFLY(1, 0, 1, 1.0f, 0.0f)
  CBFLY(0, 2, 3, 1.0f, 0.0f) CBFLY(1, 2, 3, 1.0f, 0.0f)
  CBFLY(0, 4, 5, 1.0f, 0.0f) CBFLY(1, 4, 5, 1.0f, 0.0f)
  CBFLY(0, 6, 7, 1.0f, 0.0f) CBFLY(1, 6, 7, 1.0f, 0.0f)

  // ---- final write (same slots as last read) + spectrum ----
#pragma unroll
  for (int j = 0; j < 8; ++j) {
    int p = (tid << 3) + j;
    Zs[0][ZP32(p)] = z[0][j];
    Zs[1][ZP32(p)] = z[1][j];
  }
  __syncthreads();
  float* Sb = S + (size_t)blockIdx.x * 2050;  // row = b*512 + channel-group
  for (int f = tid; f <= 1024; f += 256) {
    int rf = __brev((unsigned)f) >> 21;
    int rmf = __brev((unsigned)((2048 - f) & 2047)) >> 21;
    float pr = 0.f, pim = 0.f;
#pragma unroll
    for (int ch = 0; ch < 2; ++ch) {
      float2 zf = Zs[ch][ZP32(rf)], zm = Zs[ch][ZP32(rmf)];
      float Qr = 0.5f * (zf.x + zm.x), Qi = 0.5f * (zf.y - zm.y);
      float Kr = 0.5f * (zf.y + zm.y), Ki = -0.5f * (zf.x - zm.x);
      pr += Qr * Kr + Qi * Ki;
      pim += Qi * Kr - Qr * Ki;
    }
    Sb[2 * f] = pr;
    Sb[2 * f + 1] = pim;
  }
}

// ------------- reduce 512 partial spectrum rows -> 8-way S8 format ---------
__global__ __launch_bounds__(256) void spec_reduce_kernel(const float* __restrict__ Sbig,
                                                          float* __restrict__ S8) {
  int f = blockIdx.x * 256 + threadIdx.x;  // 0..2303, guard
  int sc = blockIdx.y;                     // 0..7 (64-row chunk)
  int b = blockIdx.z;                      // 0..7
  if (f >= 2050) return;
  const float* src = Sbig + ((size_t)b * 512 + (size_t)sc * 64) * 2050 + f;
  float s = 0.f;
  for (int i = 0; i < 64; ++i) s += src[(size_t)i * 2050];
  S8[((size_t)b * 8 + sc) * 2050 + f] = s;
}

// --------------- per-batch: inverse FFT -> mean_corr -> top-7 + softmax ----
__global__ __launch_bounds__(256) void corr_topk_kernel(const float* __restrict__ S,
                                                        int* __restrict__ delays,
                                                        float* __restrict__ alphas,
                                                        int C, int L) {
  __shared__ float2 W[2048];
  __shared__ float mc[2048];
  __shared__ float rv[4];
  __shared__ int ri[4];
  __shared__ float swv[7];
  __shared__ int sdi[7];
  int b = blockIdx.x, tid = threadIdx.x;
  const float* Sb = S + (size_t)b * 8 * 2050;
  for (int f = tid; f < 2048; f += 256) {
    int ff = f <= 1024 ? f : 2048 - f;
    float re = 0.f, im = 0.f;
    for (int s = 0; s < 8; ++s) {
      re += Sb[s * 2050 + 2 * ff];
      im += Sb[s * 2050 + 2 * ff + 1];
    }
    W[f] = make_float2(re, f <= 1024 ? -im : im);
  }
  __syncthreads();
  for (int sh = 10; sh >= 0; --sh) {
    int s = 1 << sh;
    for (int j = tid; j < 1024; j += 256) {
      int t = j & (s - 1);
      int i0 = ((j >> sh) << (sh + 1)) | t;
      int i1 = i0 + s;
      float2 a = W[i0], bb = W[i1];
      float ang = -PI_F * (float)t / (float)s;
      float sn, cs;
      __sincosf(ang, &sn, &cs);
      float2 d = make_float2(a.x - bb.x, a.y - bb.y);
      W[i0] = make_float2(a.x + bb.x, a.y + bb.y);
      W[i1] = make_float2(d.x * cs - d.y * sn, d.x * sn + d.y * cs);
    }
    __syncthreads();
  }
  float inv = 1.0f / ((float)C * (float)L);
  for (int t = tid; t < 2048; t += 256) mc[t] = W[__brev((unsigned)t) >> 21].x * inv;
  __syncthreads();
  int wv = tid >> 6, lane = tid & 63;
  for (int it = 0; it < 7; ++it) {
    float bvv = -1e30f;
    int bi = 0;
    for (int e = tid * 8; e < tid * 8 + 8; ++e) {
      float v = mc[e];
      if (v > bvv) { bvv = v; bi = e; }
    }
    for (int o = 32; o > 0; o >>= 1) {
      float ov = __shfl_down(bvv, o, 64);
      int oi = __shfl_down(bi, o, 64);
      if (ov > bvv || (ov == bvv && oi < bi)) { bvv = ov; bi = oi; }
    }
    if (lane == 0) { rv[wv] = bvv; ri[wv] = bi; }
    __syncthreads();
    if (tid == 0) {
      float fv = rv[0];
      int fi = ri[0];
      for (int w2 = 1; w2 < 4; ++w2)
        if (rv[w2] > fv || (rv[w2] == fv && ri[w2] < fi)) { fv = rv[w2]; fi = ri[w2]; }
      swv[it] = fv;
      sdi[it] = fi;
      mc[fi] = -1e30f;
    }
    __syncthreads();
  }
  if (tid == 0) {
    float mx = swv[0];
    for (int i = 1; i < 7; ++i) mx = fmaxf(mx, swv[i]);
    float e[7], s = 0.f;
    for (int i = 0; i < 7; ++i) { e[i] = expf(swv[i] - mx); s += e[i]; }
    for (int i = 0; i < 7; ++i) {
      alphas[b * 7 + i] = e[i] / s;
      delays[b * 7 + i] = sdi[i];
    }
  }
}

// ------------------- lag aggregation on xn (commuted past Wv) --------------
__global__ __launch_bounds__(256) void agg_kernel(const _Float16* __restrict__ v,
                                                  const int* __restrict__ delays,
                                                  const float* __restrict__ alphas,
                                                  _Float16* __restrict__ agg,
                                                  int L, int C) {
  int bt = blockIdx.x;
  int b = bt >> 11, t = bt & 2047;
  int tid = threadIdx.x;
  const _Float16* vb = v + (size_t)b * L * C;
  float ax = 0.f, ay = 0.f, az = 0.f, aw = 0.f;
#pragma unroll
  for (int i = 0; i < 7; ++i) {
    int d = delays[b * 7 + i];
    float a = alphas[b * 7 + i];
    int src = t + d;
    if (src >= L) src -= L;
    half4 x = ((const half4*)(vb + (size_t)src * C))[tid];
    ax += a * (float)x.x; ay += a * (float)x.y;
    az += a * (float)x.z; aw += a * (float)x.w;
  }
  half4 h = {(_Float16)ax, (_Float16)ay, (_Float16)az, (_Float16)aw};
  ((half4*)(agg + (size_t)bt * C))[tid] = h;
}

// ----------------- series decomposition: out = x - movavg25(x) -------------
template <int WRITE_H>
__global__ __launch_bounds__(256) void decomp_kernel(const float* __restrict__ xin,
                                                     float* __restrict__ xout,
                                                     _Float16* __restrict__ xh,
                                                     int L, int C) {
  int c = blockIdx.x * 256 + threadIdx.x;
  int t0 = blockIdx.y * 128;
  int b = blockIdx.z;
  const float* xb = xin + (size_t)b * L * C + c;
  float sum = 0.f;
  for (int j = t0 - 12; j <= t0 + 12; ++j) {
    int jc = j < 0 ? 0 : (j > L - 1 ? L - 1 : j);
    sum += xb[(size_t)jc * C];
  }
  for (int t = t0; t < t0 + 128; ++t) {
    float xv = xb[(size_t)t * C];
    float o = xv - sum * (1.0f / 25.0f);
    size_t oidx = ((size_t)b * L + t) * C + c;
    xout[oidx] = o;
    if (WRITE_H) xh[oidx] = (_Float16)o;
    int nj = t + 13; if (nj > L - 1) nj = L - 1;
    int oj = t - 12; if (oj < 0) oj = 0;
    sum += xb[(size_t)nj * C] - xb[(size_t)oj * C];
  }
}

// ------------------------------- launcher ----------------------------------
extern "C" void kernel_launch(void* const* d_in, const int* in_sizes, int n_in,
                              void* d_out, int out_size, void* d_ws, size_t ws_size,
                              hipStream_t stream) {
  const float* x = (const float*)d_in[0];
  const float* Wq = (const float*)d_in[1];
  const float* Wk = (const float*)d_in[2];
  const float* Wv = (const float*)d_in[3];
  const float* Wo = (const float*)d_in[4];
  const float* bo = (const float*)d_in[5];
  const float* lng = (const float*)d_in[6];
  const float* lnb = (const float*)d_in[7];
  const float* W1 = (const float*)d_in[8];
  const float* W2 = (const float*)d_in[9];
  float* out = (float*)d_out;

  const int B = 8, L = 2048, C = 1024, HD = 4096;
  const int M = B * L;  // 16384

  char* ws = (char*)d_ws;
  size_t off = 0;
  auto alloc = [&](size_t bytes) -> void* {
    void* p = ws + off;
    off = (off + bytes + 255) & ~(size_t)255;
    return p;
  };
  // ~150.6 MiB total (under the 152.1 MiB proven previously)
  _Float16* wqkh = (_Float16*)alloc((size_t)2 * C * C * 2); // 4 MB (q rows, then k rows)
  _Float16* wvoh = (_Float16*)alloc((size_t)C * C * 2);     // 2 MB (Wo*Wv)
  _Float16* w1h = (_Float16*)alloc((size_t)HD * C * 2);     // 8 MB
  _Float16* w2h = (_Float16*)alloc((size_t)C * HD * 2);     // 8 MB
  float* S8 = (float*)alloc((size_t)B * 8 * 2050 * 4);      // 512 KB (reduced spectrum)
  int* dl = (int*)alloc(B * 7 * 4);
  float* al = (float*)alloc(B * 7 * 4);
  _Float16* xn = (_Float16*)alloc((size_t)M * C * 2);       // 32 MB; later x2h
  _Float16* qkh = (_Float16*)alloc((size_t)M * 2 * C * 2);  // 64 MB [B,2C,L]; later x1/x3
  _Float16* vh = (_Float16*)alloc((size_t)4096 * 2050 * 4); // 33.6 MB: Sbig/wvT/woh, aggh, hid
  (void)ws_size; (void)in_sizes; (void)n_in; (void)out_size;

  _Float16* wvT = vh;                        // setup-only (dead before corr_fft)
  _Float16* woh = vh + (size_t)C * C;        // setup-only (dead before corr_fft)
  float* Sbig = (float*)vh;       // partial spectra (steps 5-6), dead before agg
  _Float16* aggh = vh;            // agg of xn (from step 8)
  float* x1 = (float*)qkh;        // q,k dead after corr_fft (64 MB)
  _Float16* x2h = xn;             // xn dead after agg
  float* x2 = out;                // d_out doubles as x2 scratch
  float* x3 = (float*)qkh;        // x1 dead after decomp1
  _Float16* hidc = vh;            // Sbig/aggh dead after attn GEMM (32 MB slice)

  // 1. weights -> fp16 (+ Wv transpose)
  cvt_f16_kernel<<<(C * C / 4 + 255) / 256, 256, 0, stream>>>(Wq, wqkh, C * C / 4);
  cvt_f16_kernel<<<(C * C / 4 + 255) / 256, 256, 0, stream>>>(Wk, wqkh + (size_t)C * C, C * C / 4);
  cvt_f16_kernel<<<(C * C / 4 + 255) / 256, 256, 0, stream>>>(Wo, woh, C * C / 4);
  transpose_f16_kernel<<<dim3(16, 16), 256, 0, stream>>>(Wv, wvT, C);
  cvt_f16_kernel<<<(HD * C / 4 + 255) / 256, 256, 0, stream>>>(W1, w1h, HD * C / 4);
  cvt_f16_kernel<<<(HD * C / 4 + 255) / 256, 256, 0, stream>>>(W2, w2h, HD * C / 4);
  // 2. Wvo[o,c] = sum_j Wo[o,j]*Wv[j,c]
  gemm256_kernel<4><<<16, 512, 0, stream>>>(woh, wvT, C, C, C, C, C,
                                            nullptr, wvoh, nullptr, nullptr);
  // 3. LayerNorm -> fp16
  ln_kernel<<<M, 256, 0, stream>>>(x, lng, lnb, xn, C);
  // 4. fused q,k GEMM -> transposed [B, 2C, L]
  gemm256_kernel<5><<<(M / 256) * (2 * C / 256), 512, 0, stream>>>(
      xn, wqkh, M, 2 * C, C, C, C, nullptr, qkh, nullptr, nullptr);
  // 5. channel FFTs -> per-block partial spectrum rows (no atomics)
  corr_fft_kernel<<<B * (C / 2), 256, 0, stream>>>(qkh, Sbig);
  // 6. reduce 512 partial rows -> 8-way S8
  spec_reduce_kernel<<<dim3(9, 8, 8), 256, 0, stream>>>(Sbig, S8);
  // 7. inverse FFT + top-7 + softmax
  corr_topk_kernel<<<B, 256, 0, stream>>>(S8, dl, al, C, L);
  // 8. lag aggregation on xn (commuted) -> aggh
  agg_kernel<<<B * L, 256, 0, stream>>>(xn, dl, al, aggh, L, C);
  // 9. attn = aggh * Wvo^T + bo + x -> x1 (fp32)
  gemm256_kernel<1><<<(M / 256) * (C / 256), 512, 0, stream>>>(
      aggh, wvoh, M, C, C, C, C, x1, nullptr, bo, x);
  // 10. decomp1: x2 = x1 - movavg(x1) -> d_out + fp16 copy (xn region)
  decomp_kernel<1><<<dim3(C / 256, L / 128, B), 256, 0, stream>>>(x1, x2, x2h, L, C);
  // 11. FFN: N-sliced FFN1, K-partial FFN2 (256-block dispatches)
  for (int ci = 0; ci < 4; ++ci) {
    gemm256_kernel<2><<<(M / 256) * (1024 / 256), 512, 0, stream>>>(
        x2h, w1h + (size_t)ci * 1024 * C, M, 1024, C, C, C,
        nullptr, hidc, nullptr, nullptr);
    gemm256_kernel<3><<<(M / 256) * (C / 256), 512, 0, stream>>>(
        hidc, w2h + (size_t)ci * 1024, M, C, 1024, 1024, HD,
        x3, nullptr, nullptr, ci == 0 ? x2 : x3);
  }
  // 12. decomp2 -> out
  decomp_kernel<0><<<dim3(C / 256, L / 128, B), 256, 0, stream>>>(x3, out, nullptr, L, C);
}

// Round 3
// 930.630 us; speedup vs baseline: 1.3095x; 1.0271x over previous
//
#include <hip/hip_runtime.h>
#include <cstdint>
#include <cstddef>

// ---------------------------------------------------------------------------
// AutoformerEncodeBlock R8:
//  - GEMM: m201-style dual-barrier phase skeleton on the 256x256/BK=64 8-wave
//    kernel: per phase {ds_reads; stage-issue; s_barrier; lgkmcnt(0);
//    setprio(1); 16 MFMA; setprio(0); counted-vmcnt; s_barrier}. Stage spread
//    B0,B1,B2 | B3,A0,A2 | A1 | A3 with vmcnt(6) @ph1-end, vmcnt(2) @ph3-end.
//  - corr_fft: register radix-8 FFT (R6)
//  - v-GEMM eliminated via Wvo = Wo*Wv fold; q,k fused GEMM; FFN sliced.
// ---------------------------------------------------------------------------

typedef _Float16 half8 __attribute__((ext_vector_type(8)));
typedef _Float16 half4 __attribute__((ext_vector_type(4)));
typedef float floatx4 __attribute__((ext_vector_type(4)));

#define PI_F 3.14159265358979323846f
#define ZP32(i) ((i) + ((i) >> 5))  // pad every 32 float2 elements

__device__ __forceinline__ void load_lds16(const void* g, void* l) {
  __builtin_amdgcn_global_load_lds((__attribute__((address_space(1))) void*)g,
                                   (__attribute__((address_space(3))) void*)l,
                                   16, 0, 0);
}

// ---------------------------- small utility kernels ------------------------

__global__ __launch_bounds__(256) void cvt_f16_kernel(const float* __restrict__ src,
                                                      _Float16* __restrict__ dst, int n4) {
  int i = blockIdx.x * 256 + threadIdx.x;
  if (i >= n4) return;
  float4 v = ((const float4*)src)[i];
  half4 h = {(_Float16)v.x, (_Float16)v.y, (_Float16)v.z, (_Float16)v.w};
  ((half4*)dst)[i] = h;
}

// dst[c, j] = src[j, c]  (n x n, fp32 -> fp16), 64x64 LDS tiles
__global__ __launch_bounds__(256) void transpose_f16_kernel(const float* __restrict__ src,
                                                            _Float16* __restrict__ dst, int n) {
  __shared__ float tile[64][65];
  int j0 = blockIdx.y * 64, c0 = blockIdx.x * 64;
  int tr = threadIdx.x >> 4;
  int tc = threadIdx.x & 15;
#pragma unroll
  for (int rr = 0; rr < 64; rr += 16) {
    float4 v = *(const float4*)(src + (size_t)(j0 + tr + rr) * n + c0 + tc * 4);
    tile[tr + rr][tc * 4 + 0] = v.x;
    tile[tr + rr][tc * 4 + 1] = v.y;
    tile[tr + rr][tc * 4 + 2] = v.z;
    tile[tr + rr][tc * 4 + 3] = v.w;
  }
  __syncthreads();
#pragma unroll
  for (int rr = 0; rr < 64; rr += 16) {
    int c = tr + rr;
    half4 h = {(_Float16)tile[tc * 4 + 0][c], (_Float16)tile[tc * 4 + 1][c],
               (_Float16)tile[tc * 4 + 2][c], (_Float16)tile[tc * 4 + 3][c]};
    *(half4*)(dst + (size_t)(c0 + c) * n + j0 + tc * 4) = h;
  }
}

// --------------------------------- LayerNorm -------------------------------
__global__ __launch_bounds__(256) void ln_kernel(const float* __restrict__ x,
                                                 const float* __restrict__ g,
                                                 const float* __restrict__ b,
                                                 _Float16* __restrict__ xn, int C) {
  int row = blockIdx.x;
  int t = threadIdx.x;
  const float4* xr = (const float4*)(x + (size_t)row * C);
  float4 v = xr[t];
  float s = v.x + v.y + v.z + v.w;
  float s2 = v.x * v.x + v.y * v.y + v.z * v.z + v.w * v.w;
  for (int o = 32; o > 0; o >>= 1) {
    s += __shfl_down(s, o, 64);
    s2 += __shfl_down(s2, o, 64);
  }
  __shared__ float red[8];
  int wave = t >> 6, lane = t & 63;
  if (lane == 0) { red[wave] = s; red[4 + wave] = s2; }
  __syncthreads();
  __shared__ float stats[2];
  if (t == 0) {
    float ts = red[0] + red[1] + red[2] + red[3];
    float ts2 = red[4] + red[5] + red[6] + red[7];
    float mu = ts / (float)C;
    float var = ts2 / (float)C - mu * mu;
    stats[0] = mu;
    stats[1] = 1.0f / sqrtf(var + 1e-5f);
  }
  __syncthreads();
  float mu = stats[0], rs = stats[1];
  float4 gv = ((const float4*)g)[t];
  float4 bv = ((const float4*)b)[t];
  half4 h = {(_Float16)((v.x - mu) * rs * gv.x + bv.x),
             (_Float16)((v.y - mu) * rs * gv.y + bv.y),
             (_Float16)((v.z - mu) * rs * gv.z + bv.z),
             (_Float16)((v.w - mu) * rs * gv.w + bv.w)};
  ((half4*)(xn + (size_t)row * C))[t] = h;
}

// ----------------------------------- GEMM ----------------------------------
// C[M,N] = A[M,K] * Bw[N,K]^T (fp16). 256x256 tile, BK=64, 8 waves (2x4),
// per-wave 128x64 output (acc[8][4]). 2-K-tile LDS double buffer; 8 staging
// chunks/K-tile spread 3|3|1|1 across phases (B0,B1,B2 | B3,A0,A2 | A1 | A3);
// counted vmcnt: end-ph1 vmcnt(6) guards this tile's A1/A3, end-ph3 vmcnt(2)
// guards next tile's B*+A0/A2. Per phase (m201 skeleton): ds_reads ->
// stage-issue -> s_barrier -> lgkmcnt(0) -> setprio(1) 16xMFMA setprio(0) ->
// [vmcnt] -> s_barrier. XOR-granule swizzle: source pre-swizzled (l7^l3),
// ds_read applies granule^(row&7). Zero bank conflicts (verified R7).
// EPI: 1 = +bias[col]+res fp32, 2 = GELU -> fp16, 3 = +res fp32 (RMW ok),
//      4 = plain fp16, 5 = fp16 transposed [B, N, L] (L=2048)
template <int EPI>
__global__ __launch_bounds__(512, 2) void gemm256_kernel(
    const _Float16* __restrict__ A, const _Float16* __restrict__ Bw,
    int M, int N, int K, int lda, int ldb,
    float* __restrict__ outf, _Float16* __restrict__ outh,
    const float* __restrict__ bias, const float* __restrict__ res) {
  __shared__ _Float16 lds[2][2][256 * 64];  // [buf][A=0/B=1][256 rows x 64 halfs]

  int tid = threadIdx.x;
  int lane = tid & 63;
  int wave = tid >> 6;          // 0..7
  int wm = wave >> 2;           // 0..1  (M half)
  int wn = wave & 3;            // 0..3  (N quarter)
  int ln15 = lane & 15, q4 = lane >> 4;
  int l3 = lane >> 3, l7 = lane & 7;

  int nwg = gridDim.x, orig = blockIdx.x;
  int wg = ((nwg & 7) == 0) ? ((orig & 7) * (nwg >> 3) + (orig >> 3)) : orig;
  int nbn = N >> 8;
  size_t m0 = (size_t)(wg / nbn) << 8;
  size_t n0 = (size_t)(wg % nbn) << 8;

  // swizzled ds_read granule offsets (halfs)
  int sg0 = (q4 ^ l7) << 3;         // kk=0
  int sg1 = ((q4 + 4) ^ l7) << 3;   // kk=32

  floatx4 acc[8][4] = {};

  // staging: lane covers row (8*wave + l3) of each 64-row chunk, global
  // granule pre-swizzled to l7^l3 so linear LDS dest == swizzled layout.
  const _Float16* srcA = A + (m0 + 8 * wave + l3) * (size_t)lda + (size_t)((l7 ^ l3) * 8);
  const _Float16* srcB = Bw + (n0 + 8 * wave + l3) * (size_t)ldb + (size_t)((l7 ^ l3) * 8);
  char* ldsA0 = (char*)&lds[0][0][0] + wave * 1024;
  char* ldsB0 = (char*)&lds[0][1][0] + wave * 1024;

  // prologue: stage tile 0 (order B0,B1,B2,B3,A0,A2,A1,A3) into buf 0
  load_lds16(srcB, ldsB0);
  load_lds16(srcB + (size_t)64 * ldb, ldsB0 + 1 * 8192);
  load_lds16(srcB + (size_t)128 * ldb, ldsB0 + 2 * 8192);
  load_lds16(srcB + (size_t)192 * ldb, ldsB0 + 3 * 8192);
  load_lds16(srcA, ldsA0);
  load_lds16(srcA + (size_t)128 * lda, ldsA0 + 2 * 8192);
  load_lds16(srcA + (size_t)64 * lda, ldsA0 + 1 * 8192);
  load_lds16(srcA + (size_t)192 * lda, ldsA0 + 3 * 8192);
  // guard tile-0 reads (A1,A3 may stay outstanding)
  asm volatile("s_waitcnt vmcnt(2)" ::: "memory");
  __builtin_amdgcn_s_barrier();
  __builtin_amdgcn_sched_barrier(0);

  int nk = K >> 6;
  half8 bf[4][2], aA[2][2];

#define RD_B() _Pragma("unroll") for (int ni = 0; ni < 4; ++ni) {      \
    const _Float16* p_ = cB + ((wn * 64 + ni * 16 + ln15) << 6);       \
    bf[ni][0] = *(const half8*)(p_ + sg0);                             \
    bf[ni][1] = *(const half8*)(p_ + sg1); }
#define RD_A(mi) { const _Float16* p_ = cA + ((wm * 128 + (mi) * 16 + ln15) << 6); \
    aA[(mi) & 1][0] = *(const half8*)(p_ + sg0);                                   \
    aA[(mi) & 1][1] = *(const half8*)(p_ + sg1); }
#define MM(mi) _Pragma("unroll") for (int ni = 0; ni < 4; ++ni) {      \
    acc[mi][ni] = __builtin_amdgcn_mfma_f32_16x16x32_f16(aA[(mi) & 1][0], bf[ni][0], acc[mi][ni], 0, 0, 0); \
    acc[mi][ni] = __builtin_amdgcn_mfma_f32_16x16x32_f16(aA[(mi) & 1][1], bf[ni][1], acc[mi][ni], 0, 0, 0); }

#define PH_MID()                                            \
    __builtin_amdgcn_s_barrier();                           \
    asm volatile("s_waitcnt lgkmcnt(0)" ::: "memory");      \
    __builtin_amdgcn_sched_barrier(0);                      \
    __builtin_amdgcn_s_setprio(1);
#define PH_END()                                            \
    __builtin_amdgcn_s_setprio(0);                          \
    __builtin_amdgcn_s_barrier();                           \
    __builtin_amdgcn_sched_barrier(0);

  for (int t = 0; t < nk; ++t) {
    int cur = t & 1;
    const _Float16* cA = &lds[cur][0][0];
    const _Float16* cB = &lds[cur][1][0];
    const _Float16* As = srcA + (size_t)(t + 1) * 64;
    const _Float16* Bs = srcB + (size_t)(t + 1) * 64;
    char* stA = ldsA0 + (cur ^ 1) * 65536;
    char* stB = ldsB0 + (cur ^ 1) * 65536;
    bool pf = (t + 1 < nk);

    // ---- phase 0: MFMA mi=0,1 ----
    RD_B();
    RD_A(0); RD_A(1);
    if (pf) {
      load_lds16(Bs, stB);
      load_lds16(Bs + (size_t)64 * ldb, stB + 1 * 8192);
      load_lds16(Bs + (size_t)128 * ldb, stB + 2 * 8192);
    }
    PH_MID();
    MM(0); MM(1);
    PH_END();
    // ---- phase 1: MFMA mi=2,3; end-wait guards this tile's A1,A3 ----
    RD_A(2); RD_A(3);
    if (pf) {
      load_lds16(Bs + (size_t)192 * ldb, stB + 3 * 8192);
      load_lds16(As, stA);
      load_lds16(As + (size_t)128 * lda, stA + 2 * 8192);
    }
    PH_MID();
    MM(2); MM(3);
    __builtin_amdgcn_s_setprio(0);
    if (pf) {
      asm volatile("s_waitcnt vmcnt(6)" ::: "memory");
    } else {
      asm volatile("s_waitcnt vmcnt(0)" ::: "memory");
    }
    __builtin_amdgcn_s_barrier();
    __builtin_amdgcn_sched_barrier(0);
    // ---- phase 2: MFMA mi=4,5 ----
    RD_A(4); RD_A(5);
    if (pf) {
      load_lds16(As + (size_t)64 * lda, stA + 1 * 8192);
    }
    PH_MID();
    MM(4); MM(5);
    PH_END();
    // ---- phase 3: MFMA mi=6,7; end-wait guards next tile's B*,A0,A2 ----
    RD_A(6); RD_A(7);
    if (pf) {
      load_lds16(As + (size_t)192 * lda, stA + 3 * 8192);
    }
    PH_MID();
    MM(6); MM(7);
    __builtin_amdgcn_s_setprio(0);
    asm volatile("s_waitcnt vmcnt(2)" ::: "memory");
    __builtin_amdgcn_s_barrier();
    __builtin_amdgcn_sched_barrier(0);
  }
#undef RD_B
#undef RD_A
#undef MM
#undef PH_MID
#undef PH_END

#pragma unroll
  for (int mi = 0; mi < 8; ++mi) {
#pragma unroll
    for (int ni = 0; ni < 4; ++ni) {
      floatx4 a4 = acc[mi][ni];
      size_t rowb = m0 + wm * 128 + mi * 16 + q4 * 4;
      size_t col = n0 + wn * 64 + ni * 16 + ln15;
      if (EPI == 5) {
        size_t b = rowb >> 11, l0 = rowb & 2047;
        half4 h = {(_Float16)a4[0], (_Float16)a4[1], (_Float16)a4[2], (_Float16)a4[3]};
        *(half4*)(outh + (((size_t)b * N + col) << 11) + l0) = h;
      } else {
#pragma unroll
        for (int r = 0; r < 4; ++r) {
          size_t idx = (rowb + r) * (size_t)N + col;
          float v = a4[r];
          if (EPI == 1) {
            outf[idx] = v + bias[col] + res[idx];
          } else if (EPI == 2) {
            float ge = 0.5f * v * (1.0f + erff(v * 0.70710678118654752f));
            outh[idx] = (_Float16)ge;
          } else if (EPI == 3) {
            outf[idx] = v + res[idx];
          } else {
            outh[idx] = (_Float16)v;
          }
        }
      }
    }
  }
}

// --------------------- autocorrelation: register radix-8 FFT ---------------
// qk fused transposed layout F[b, ch, l], ch<1024 = q, ch>=1024 = k.
// block = (b, 2 channel-pairs), 256 threads. z = q + i*k; 2048-pt radix-2
// DIF FFT where 3 stages at a time run in registers (thread t holds 8 pts),
// separated by pad-32 conflict-free LDS exchanges. Hermitian split; partial
// spectrum row per block (no atomics), reduced by spec_reduce_kernel.

#define CBFLY(ch, ia, ib, wr, wi) {                      \
    float ax_ = z[ch][ia].x, ay_ = z[ch][ia].y;          \
    float bx_ = z[ch][ib].x, by_ = z[ch][ib].y;          \
    float dx_ = ax_ - bx_, dy_ = ay_ - by_;              \
    z[ch][ia].x = ax_ + bx_; z[ch][ia].y = ay_ + by_;    \
    z[ch][ib].x = dx_ * (wr) - dy_ * (wi);               \
    z[ch][ib].y = dx_ * (wi) + dy_ * (wr); }
#define BFLY2(ia, ib, m) { float2 w_ = twl[ZP32(m)];     \
    CBFLY(0, ia, ib, w_.x, w_.y) CBFLY(1, ia, ib, w_.x, w_.y) }

__global__ __launch_bounds__(256) void corr_fft_kernel(const _Float16* __restrict__ F,
                                                       float* __restrict__ S) {
  __shared__ float2 Zs[2][2112];   // 2048 + pad every 32
  __shared__ float2 twl[1056];     // 1024 twiddles, padded
  int tid = threadIdx.x;
  int b = blockIdx.x >> 9;
  int c0 = (blockIdx.x & 511) << 1;
  const _Float16* qb = F + ((size_t)(b * 2048 + c0) << 11);
  const _Float16* kb = F + ((size_t)(b * 2048 + 1024 + c0) << 11);

  // load 8 points per channel per thread: positions t + 256*j
  float2 z[2][8];
#pragma unroll
  for (int j = 0; j < 8; ++j) {
    int p = tid + 256 * j;
    z[0][j] = make_float2((float)qb[p], (float)kb[p]);
    z[1][j] = make_float2((float)qb[2048 + p], (float)kb[2048 + p]);
  }
  // twiddle table: twl[m] = exp(-2*pi*i*m/2048)
  for (int m = tid; m < 1024; m += 256) {
    float sn, cs;
    __sincosf(-PI_F * (float)m / 1024.0f, &sn, &cs);
    twl[ZP32(m)] = make_float2(cs, sn);
  }
  __syncthreads();

  // ---- round 1: stages sh=10,9,8  (positions t + 256j) ----
  BFLY2(0, 4, tid)
  BFLY2(1, 5, tid + 256)
  BFLY2(2, 6, tid + 512)
  BFLY2(3, 7, tid + 768)
  { float2 wA = twl[ZP32(tid << 1)], wB = twl[ZP32((tid + 256) << 1)];
    CBFLY(0, 0, 2, wA.x, wA.y) CBFLY(1, 0, 2, wA.x, wA.y)
    CBFLY(0, 1, 3, wB.x, wB.y) CBFLY(1, 1, 3, wB.x, wB.y)
    CBFLY(0, 4, 6, wA.x, wA.y) CBFLY(1, 4, 6, wA.x, wA.y)
    CBFLY(0, 5, 7, wB.x, wB.y) CBFLY(1, 5, 7, wB.x, wB.y) }
  { float2 wA = twl[ZP32(tid << 2)];
    CBFLY(0, 0, 1, wA.x, wA.y) CBFLY(1, 0, 1, wA.x, wA.y)
    CBFLY(0, 2, 3, wA.x, wA.y) CBFLY(1, 2, 3, wA.x, wA.y)
    CBFLY(0, 4, 5, wA.x, wA.y) CBFLY(1, 4, 5, wA.x, wA.y)
    CBFLY(0, 6, 7, wA.x, wA.y) CBFLY(1, 6, 7, wA.x, wA.y) }

  // ---- exchange 1: write t+256j, read (t>>5)*256 + (t&31) + 32j ----
#pragma unroll
  for (int j = 0; j < 8; ++j) {
    int p = tid + 256 * j;
    Zs[0][ZP32(p)] = z[0][j];
    Zs[1][ZP32(p)] = z[1][j];
  }
  __syncthreads();
  int t5 = tid & 31, hi1 = (tid >> 5) << 8;
#pragma unroll
  for (int j = 0; j < 8; ++j) {
    int p = hi1 + t5 + 32 * j;
    z[0][j] = Zs[0][ZP32(p)];
    z[1][j] = Zs[1][ZP32(p)];
  }

  // ---- round 2: stages sh=7,6,5 ----
  BFLY2(0, 4, t5 << 3)
  BFLY2(1, 5, (t5 + 32) << 3)
  BFLY2(2, 6, (t5 + 64) << 3)
  BFLY2(3, 7, (t5 + 96) << 3)
  { float2 wA = twl[ZP32(t5 << 4)], wB = twl[ZP32((t5 + 32) << 4)];
    CBFLY(0, 0, 2, wA.x, wA.y) CBFLY(1, 0, 2, wA.x, wA.y)
    CBFLY(0, 1, 3, wB.x, wB.y) CBFLY(1, 1, 3, wB.x, wB.y)
    CBFLY(0, 4, 6, wA.x, wA.y) CBFLY(1, 4, 6, wA.x, wA.y)
    CBFLY(0, 5, 7, wB.x, wB.y) CBFLY(1, 5, 7, wB.x, wB.y) }
  { float2 wA = twl[ZP32(t5 << 5)];
    CBFLY(0, 0, 1, wA.x, wA.y) CBFLY(1, 0, 1, wA.x, wA.y)
    CBFLY(0, 2, 3, wA.x, wA.y) CBFLY(1, 2, 3, wA.x, wA.y)
    CBFLY(0, 4, 5, wA.x, wA.y) CBFLY(1, 4, 5, wA.x, wA.y)
    CBFLY(0, 6, 7, wA.x, wA.y) CBFLY(1, 6, 7, wA.x, wA.y) }

  // ---- exchange 2: write back same slots, read (t>>2)*32 + (t&3) + 4j ----
  // (each slot was read only by this thread -> no barrier before write)
#pragma unroll
  for (int j = 0; j < 8; ++j) {
    int p = hi1 + t5 + 32 * j;
    Zs[0][ZP32(p)] = z[0][j];
    Zs[1][ZP32(p)] = z[1][j];
  }
  __syncthreads();
  int t3 = tid & 3, hi2 = (tid >> 2) << 5;
#pragma unroll
  for (int j = 0; j < 8; ++j) {
    int p = hi2 + t3 + 4 * j;
    z[0][j] = Zs[0][ZP32(p)];
    z[1][j] = Zs[1][ZP32(p)];
  }

  // ---- round 3: stages sh=4,3,2 ----
  BFLY2(0, 4, t3 << 6)
  BFLY2(1, 5, (t3 + 4) << 6)
  BFLY2(2, 6, (t3 + 8) << 6)
  BFLY2(3, 7, (t3 + 12) << 6)
  { float2 wA = twl[ZP32(t3 << 7)], wB = twl[ZP32((t3 + 4) << 7)];
    CBFLY(0, 0, 2, wA.x, wA.y) CBFLY(1, 0, 2, wA.x, wA.y)
    CBFLY(0, 1, 3, wB.x, wB.y) CBFLY(1, 1, 3, wB.x, wB.y)
    CBFLY(0, 4, 6, wA.x, wA.y) CBFLY(1, 4, 6, wA.x, wA.y)
    CBFLY(0, 5, 7, wB.x, wB.y) CBFLY(1, 5, 7, wB.x, wB.y) }
  { float2 wA = twl[ZP32(t3 << 8)];
    CBFLY(0, 0, 1, wA.x, wA.y) CBFLY(1, 0, 1, wA.x, wA.y)
    CBFLY(0, 2, 3, wA.x, wA.y) CBFLY(1, 2, 3, wA.x, wA.y)
    CBFLY(0, 4, 5, wA.x, wA.y) CBFLY(1, 4, 5, wA.x, wA.y)
    CBFLY(0, 6, 7, wA.x, wA.y) CBFLY(1, 6, 7, wA.x, wA.y) }

  // ---- exchange 3: write back same slots, read 8t + j ----
#pragma unroll
  for (int j = 0; j < 8; ++j) {
    int p = hi2 + t3 + 4 * j;
    Zs[0][ZP32(p)] = z[0][j];
    Zs[1][ZP32(p)] = z[1][j];
  }
  __syncthreads();
#pragma unroll
  for (int j = 0; j < 8; ++j) {
    int p = (tid << 3) + j;
    z[0][j] = Zs[0][ZP32(p)];
    z[1][j] = Zs[1][ZP32(p)];
  }

  // ---- round 4: stages sh=1 (w = 1 or -i), sh=0 (w = 1) ----
  CBFLY(0, 0, 2, 1.0f, 0.0f) CBFLY(1, 0, 2, 1.0f, 0.0f)
  CBFLY(0, 1, 3, 0.0f, -1.0f) CBFLY(1, 1, 3, 0.0f, -1.0f)
  CBFLY(0, 4, 6, 1.0f, 0.0f) CBFLY(1, 4, 6, 1.0f, 0.0f)
  CBFLY(0, 5, 7, 0.0f, -1.0f) CBFLY(1, 5, 7, 0.0f, -1.0f)
  CBFLY(0, 0, 1, 1.0f, 0.0f) CBFLY(1, 0, 1, 1.0f, 0.0f)
  CBFLY(0, 2, 3, 1.0f, 0.0f) CBFLY(1, 2, 3, 1.0f, 0.0f)
  CBFLY(0, 4, 5, 1.0f, 0.0f) CBFLY(1, 4, 5, 1.0f, 0.0f)
  CBFLY(0, 6, 7, 1.0f, 0.0f) CBFLY(1, 6, 7, 1.0f, 0.0f)

  // ---- final write (same slots as last read) + spectrum ----
#pragma unroll
  for (int j = 0; j < 8; ++j) {
    int p = (tid << 3) + j;
    Zs[0][ZP32(p)] = z[0][j];
    Zs[1][ZP32(p)] = z[1][j];
  }
  __syncthreads();
  float* Sb = S + (size_t)blockIdx.x * 2050;  // row = b*512 + channel-group
  for (int f = tid; f <= 1024; f += 256) {
    int rf = __brev((unsigned)f) >> 21;
    int rmf = __brev((unsigned)((2048 - f) & 2047)) >> 21;
    float pr = 0.f, pim = 0.f;
#pragma unroll
    for (int ch = 0; ch < 2; ++ch) {
      float2 zf = Zs[ch][ZP32(rf)], zm = Zs[ch][ZP32(rmf)];
      float Qr = 0.5f * (zf.x + zm.x), Qi = 0.5f * (zf.y - zm.y);
      float Kr = 0.5f * (zf.y + zm.y), Ki = -0.5f * (zf.x - zm.x);
      pr += Qr * Kr + Qi * Ki;
      pim += Qi * Kr - Qr * Ki;
    }
    Sb[2 * f] = pr;
    Sb[2 * f + 1] = pim;
  }
}

// ------------- reduce 512 partial spectrum rows -> 8-way S8 format ---------
__global__ __launch_bounds__(256) void spec_reduce_kernel(const float* __restrict__ Sbig,
                                                          float* __restrict__ S8) {
  int f = blockIdx.x * 256 + threadIdx.x;  // 0..2303, guard
  int sc = blockIdx.y;                     // 0..7 (64-row chunk)
  int b = blockIdx.z;                      // 0..7
  if (f >= 2050) return;
  const float* src = Sbig + ((size_t)b * 512 + (size_t)sc * 64) * 2050 + f;
  float s = 0.f;
  for (int i = 0; i < 64; ++i) s += src[(size_t)i * 2050];
  S8[((size_t)b * 8 + sc) * 2050 + f] = s;
}

// --------------- per-batch: inverse FFT -> mean_corr -> top-7 + softmax ----
__global__ __launch_bounds__(256) void corr_topk_kernel(const float* __restrict__ S,
                                                        int* __restrict__ delays,
                                                        float* __restrict__ alphas,
                                                        int C, int L) {
  __shared__ float2 W[2048];
  __shared__ float mc[2048];
  __shared__ float rv[4];
  __shared__ int ri[4];
  __shared__ float swv[7];
  __shared__ int sdi[7];
  int b = blockIdx.x, tid = threadIdx.x;
  const float* Sb = S + (size_t)b * 8 * 2050;
  for (int f = tid; f < 2048; f += 256) {
    int ff = f <= 1024 ? f : 2048 - f;
    float re = 0.f, im = 0.f;
    for (int s = 0; s < 8; ++s) {
      re += Sb[s * 2050 + 2 * ff];
      im += Sb[s * 2050 + 2 * ff + 1];
    }
    W[f] = make_float2(re, f <= 1024 ? -im : im);
  }
  __syncthreads();
  for (int sh = 10; sh >= 0; --sh) {
    int s = 1 << sh;
    for (int j = tid; j < 1024; j += 256) {
      int t = j & (s - 1);
      int i0 = ((j >> sh) << (sh + 1)) | t;
      int i1 = i0 + s;
      float2 a = W[i0], bb = W[i1];
      float ang = -PI_F * (float)t / (float)s;
      float sn, cs;
      __sincosf(ang, &sn, &cs);
      float2 d = make_float2(a.x - bb.x, a.y - bb.y);
      W[i0] = make_float2(a.x + bb.x, a.y + bb.y);
      W[i1] = make_float2(d.x * cs - d.y * sn, d.x * sn + d.y * cs);
    }
    __syncthreads();
  }
  float inv = 1.0f / ((float)C * (float)L);
  for (int t = tid; t < 2048; t += 256) mc[t] = W[__brev((unsigned)t) >> 21].x * inv;
  __syncthreads();
  int wv = tid >> 6, lane = tid & 63;
  for (int it = 0; it < 7; ++it) {
    float bvv = -1e30f;
    int bi = 0;
    for (int e = tid * 8; e < tid * 8 + 8; ++e) {
      float v = mc[e];
      if (v > bvv) { bvv = v; bi = e; }
    }
    for (int o = 32; o > 0; o >>= 1) {
      float ov = __shfl_down(bvv, o, 64);
      int oi = __shfl_down(bi, o, 64);
      if (ov > bvv || (ov == bvv && oi < bi)) { bvv = ov; bi = oi; }
    }
    if (lane == 0) { rv[wv] = bvv; ri[wv] = bi; }
    __syncthreads();
    if (tid == 0) {
      float fv = rv[0];
      int fi = ri[0];
      for (int w2 = 1; w2 < 4; ++w2)
        if (rv[w2] > fv || (rv[w2] == fv && ri[w2] < fi)) { fv = rv[w2]; fi = ri[w2]; }
      swv[it] = fv;
      sdi[it] = fi;
      mc[fi] = -1e30f;
    }
    __syncthreads();
  }
  if (tid == 0) {
    float mx = swv[0];
    for (int i = 1; i < 7; ++i) mx = fmaxf(mx, swv[i]);
    float e[7], s = 0.f;
    for (int i = 0; i < 7; ++i) { e[i] = expf(swv[i] - mx); s += e[i]; }
    for (int i = 0; i < 7; ++i) {
      alphas[b * 7 + i] = e[i] / s;
      delays[b * 7 + i] = sdi[i];
    }
  }
}

// ------------------- lag aggregation on xn (commuted past Wv) --------------
__global__ __launch_bounds__(256) void agg_kernel(const _Float16* __restrict__ v,
                                                  const int* __restrict__ delays,
                                                  const float* __restrict__ alphas,
                                                  _Float16* __restrict__ agg,
                                                  int L, int C) {
  int bt = blockIdx.x;
  int b = bt >> 11, t = bt & 2047;
  int tid = threadIdx.x;
  const _Float16* vb = v + (size_t)b * L * C;
  float ax = 0.f, ay = 0.f, az = 0.f, aw = 0.f;
#pragma unroll
  for (int i = 0; i < 7; ++i) {
    int d = delays[b * 7 + i];
    float a = alphas[b * 7 + i];
    int src = t + d;
    if (src >= L) src -= L;
    half4 x = ((const half4*)(vb + (size_t)src * C))[tid];
    ax += a * (float)x.x; ay += a * (float)x.y;
    az += a * (float)x.z; aw += a * (float)x.w;
  }
  half4 h = {(_Float16)ax, (_Float16)ay, (_Float16)az, (_Float16)aw};
  ((half4*)(agg + (size_t)bt * C))[tid] = h;
}

// ----------------- series decomposition: out = x - movavg25(x) -------------
template <int WRITE_H>
__global__ __launch_bounds__(256) void decomp_kernel(const float* __restrict__ xin,
                                                     float* __restrict__ xout,
                                                     _Float16* __restrict__ xh,
                                                     int L, int C) {
  int c = blockIdx.x * 256 + threadIdx.x;
  int t0 = blockIdx.y * 128;
  int b = blockIdx.z;
  const float* xb = xin + (size_t)b * L * C + c;
  float sum = 0.f;
  for (int j = t0 - 12; j <= t0 + 12; ++j) {
    int jc = j < 0 ? 0 : (j > L - 1 ? L - 1 : j);
    sum += xb[(size_t)jc * C];
  }
  for (int t = t0; t < t0 + 128; ++t) {
    float xv = xb[(size_t)t * C];
    float o = xv - sum * (1.0f / 25.0f);
    size_t oidx = ((size_t)b * L + t) * C + c;
    xout[oidx] = o;
    if (WRITE_H) xh[oidx] = (_Float16)o;
    int nj = t + 13; if (nj > L - 1) nj = L - 1;
    int oj = t - 12; if (oj < 0) oj = 0;
    sum += xb[(size_t)nj * C] - xb[(size_t)oj * C];
  }
}

// ------------------------------- launcher ----------------------------------
extern "C" void kernel_launch(void* const* d_in, const int* in_sizes, int n_in,
                              void* d_out, int out_size, void* d_ws, size_t ws_size,
                              hipStream_t stream) {
  const float* x = (const float*)d_in[0];
  const float* Wq = (const float*)d_in[1];
  const float* Wk = (const float*)d_in[2];
  const float* Wv = (const float*)d_in[3];
  const float* Wo = (const float*)d_in[4];
  const float* bo = (const float*)d_in[5];
  const float* lng = (const float*)d_in[6];
  const float* lnb = (const float*)d_in[7];
  const float* W1 = (const float*)d_in[8];
  const float* W2 = (const float*)d_in[9];
  float* out = (float*)d_out;

  const int B = 8, L = 2048, C = 1024, HD = 4096;
  const int M = B * L;  // 16384

  char* ws = (char*)d_ws;
  size_t off = 0;
  auto alloc = [&](size_t bytes) -> void* {
    void* p = ws + off;
    off = (off + bytes + 255) & ~(size_t)255;
    return p;
  };
  // ~150.6 MiB total (under the 152.1 MiB proven previously)
  _Float16* wqkh = (_Float16*)alloc((size_t)2 * C * C * 2); // 4 MB (q rows, then k rows)
  _Float16* wvoh = (_Float16*)alloc((size_t)C * C * 2);     // 2 MB (Wo*Wv)
  _Float16* w1h = (_Float16*)alloc((size_t)HD * C * 2);     // 8 MB
  _Float16* w2h = (_Float16*)alloc((size_t)C * HD * 2);     // 8 MB
  float* S8 = (float*)alloc((size_t)B * 8 * 2050 * 4);      // 512 KB (reduced spectrum)
  int* dl = (int*)alloc(B * 7 * 4);
  float* al = (float*)alloc(B * 7 * 4);
  _Float16* xn = (_Float16*)alloc((size_t)M * C * 2);       // 32 MB; later x2h
  _Float16* qkh = (_Float16*)alloc((size_t)M * 2 * C * 2);  // 64 MB [B,2C,L]; later x1/x3
  _Float16* vh = (_Float16*)alloc((size_t)4096 * 2050 * 4); // 33.6 MB: Sbig/wvT/woh, aggh, hid
  (void)ws_size; (void)in_sizes; (void)n_in; (void)out_size;

  _Float16* wvT = vh;                        // setup-only (dead before corr_fft)
  _Float16* woh = vh + (size_t)C * C;        // setup-only (dead before corr_fft)
  float* Sbig = (float*)vh;       // partial spectra (steps 5-6), dead before agg
  _Float16* aggh = vh;            // agg of xn (from step 8)
  float* x1 = (float*)qkh;        // q,k dead after corr_fft (64 MB)
  _Float16* x2h = xn;             // xn dead after agg
  float* x2 = out;                // d_out doubles as x2 scratch
  float* x3 = (float*)qkh;        // x1 dead after decomp1
  _Float16* hidc = vh;            // Sbig/aggh dead after attn GEMM (32 MB slice)

  // 1. weights -> fp16 (+ Wv transpose)
  cvt_f16_kernel<<<(C * C / 4 + 255) / 256, 256, 0, stream>>>(Wq, wqkh, C * C / 4);
  cvt_f16_kernel<<<(C * C / 4 + 255) / 256, 256, 0, stream>>>(Wk, wqkh + (size_t)C * C, C * C / 4);
  cvt_f16_kernel<<<(C * C / 4 + 255) / 256, 256, 0, stream>>>(Wo, woh, C * C / 4);
  transpose_f16_kernel<<<dim3(16, 16), 256, 0, stream>>>(Wv, wvT, C);
  cvt_f16_kernel<<<(HD * C / 4 + 255) / 256, 256, 0, stream>>>(W1, w1h, HD * C / 4);
  cvt_f16_kernel<<<(HD * C / 4 + 255) / 256, 256, 0, stream>>>(W2, w2h, HD * C / 4);
  // 2. Wvo[o,c] = sum_j Wo[o,j]*Wv[j,c]
  gemm256_kernel<4><<<16, 512, 0, stream>>>(woh, wvT, C, C, C, C, C,
                                            nullptr, wvoh, nullptr, nullptr);
  // 3. LayerNorm -> fp16
  ln_kernel<<<M, 256, 0, stream>>>(x, lng, lnb, xn, C);
  // 4. fused q,k GEMM -> transposed [B, 2C, L]
  gemm256_kernel<5><<<(M / 256) * (2 * C / 256), 512, 0, stream>>>(
      xn, wqkh, M, 2 * C, C, C, C, nullptr, qkh, nullptr, nullptr);
  // 5. channel FFTs -> per-block partial spectrum rows (no atomics)
  corr_fft_kernel<<<B * (C / 2), 256, 0, stream>>>(qkh, Sbig);
  // 6. reduce 512 partial rows -> 8-way S8
  spec_reduce_kernel<<<dim3(9, 8, 8), 256, 0, stream>>>(Sbig, S8);
  // 7. inverse FFT + top-7 + softmax
  corr_topk_kernel<<<B, 256, 0, stream>>>(S8, dl, al, C, L);
  // 8. lag aggregation on xn (commuted) -> aggh
  agg_kernel<<<B * L, 256, 0, stream>>>(xn, dl, al, aggh, L, C);
  // 9. attn = aggh * Wvo^T + bo + x -> x1 (fp32)
  gemm256_kernel<1><<<(M / 256) * (C / 256), 512, 0, stream>>>(
      aggh, wvoh, M, C, C, C, C, x1, nullptr, bo, x);
  // 10. decomp1: x2 = x1 - movavg(x1) -> d_out + fp16 copy (xn region)
  decomp_kernel<1><<<dim3(C / 256, L / 128, B), 256, 0, stream>>>(x1, x2, x2h, L, C);
  // 11. FFN: N-sliced FFN1, K-partial FFN2 (256-block dispatches)
  for (int ci = 0; ci < 4; ++ci) {
    gemm256_kernel<2><<<(M / 256) * (1024 / 256), 512, 0, stream>>>(
        x2h, w1h + (size_t)ci * 1024 * C, M, 1024, C, C, C,
        nullptr, hidc, nullptr, nullptr);
    gemm256_kernel<3><<<(M / 256) * (C / 256), 512, 0, stream>>>(
        hidc, w2h + (size_t)ci * 1024, M, C, 1024, 1024, HD,
        x3, nullptr, nullptr, ci == 0 ? x2 : x3);
  }
  // 12. decomp2 -> out
  decomp_kernel<0><<<dim3(C / 256, L / 128, B), 256, 0, stream>>>(x3, out, nullptr, L, C);
}